// Round 4
// baseline (587.066 us; speedup 1.0000x reference)
//
#include <hip/hip_runtime.h>
#include <stdint.h>

#define SEQ   2048
#define NTOK  8192   // 4 * 2048

typedef unsigned short u16;
typedef __bf16 bf16x8 __attribute__((ext_vector_type(8)));
typedef float  f32x4  __attribute__((ext_vector_type(4)));
typedef float  f32x16 __attribute__((ext_vector_type(16)));

__device__ __forceinline__ float b2f(u16 b) {
    union { unsigned u; float f; } v; v.u = ((unsigned)b) << 16; return v.f;
}
__device__ __forceinline__ u16 f2b(float f) {
    union { float f; unsigned u; } v; v.f = f;
    unsigned r = (v.u + 0x7fffu + ((v.u >> 16) & 1u)) >> 16;
    return (u16)r;
}
__device__ __forceinline__ u16 f2b_trunc(float f) {   // cheap, P >= 0
    union { float f; unsigned u; } v; v.f = f;
    return (u16)(v.u >> 16);
}

__device__ __forceinline__ void gl_lds16(const void* g, void* l) {
    __builtin_amdgcn_global_load_lds(
        (const __attribute__((address_space(1))) void*)g,
        (__attribute__((address_space(3))) void*)l,
        16, 0, 0);
}

// ---------------------------------------------------------------------------
// fp32 -> bf16 conversion, all 7 weight matrices in ONE dispatch.
// gate/up are interleaved into ONE combined matrix dmu[8192][1024]:
//   rows [32q..32q+16) = gate rows [16q..16q+16)
//   rows [32q+16..32q+32) = up rows [16q..16q+16)
// so the 8-phase MLP GEMM can pair gate/up register-locally (16-col frags).
// ---------------------------------------------------------------------------
__global__ __launch_bounds__(256)
void cvt_all(const float* __restrict__ wq, const float* __restrict__ wk,
             const float* __restrict__ wv, const float* __restrict__ wo,
             const float* __restrict__ wup, const float* __restrict__ wgt,
             const float* __restrict__ wdn,
             u16* __restrict__ dq, u16* __restrict__ dk, u16* __restrict__ dv,
             u16* __restrict__ dw, u16* __restrict__ dmu, u16* __restrict__ dd)
{
    const int bid = blockIdx.x;
    const float* s; u16* d; int osrc, odst;
    if (bid < 4096) {
        const int which = bid >> 10;
        osrc = odst = (bid & 1023) * 256 + threadIdx.x;
        s = which == 0 ? wq : which == 1 ? wk : which == 2 ? wv : wo;
        d = which == 0 ? dq : which == 1 ? dk : which == 2 ? dv : dw;
    } else {
        const int which = (bid - 4096) >> 12;     // 0=up 1=gate 2=down
        const int o = ((bid - 4096) & 4095) * 256 + threadIdx.x;
        osrc = o;
        if (which == 2) { s = wdn; d = dd; odst = o; }
        else {
            s = which == 0 ? wup : wgt;
            d = dmu;
            const int row = o >> 8;               // 256 float4 per 1024-col row
            const int rowp = ((row >> 4) << 5) + (row & 15) + (which == 0 ? 16 : 0);
            odst = rowp * 256 + (o & 255);
        }
    }
    float4 v = ((const float4*)s)[osrc];
    ushort4 ov;
    ov.x = f2b(v.x); ov.y = f2b(v.y); ov.z = f2b(v.z); ov.w = f2b(v.w);
    ((ushort4*)d)[odst] = ov;
}

// ---------------------------------------------------------------------------
// GEMM: C[M][N] = A[M][K] * B[N][K]^T   (bf16 in, fp32 accum)
// 128x128 tile, BK=64, XOR-swizzled LDS, mfma 32x32x16.
// EPI 0: bf16 C[idx] = acc
// EPI 1: f32  C[idx] = acc + E_f32[idx]          (fused residual, fp32 out)
// ---------------------------------------------------------------------------
template<int EPI>
__global__ __launch_bounds__(256)
void gemm_bt(const u16* __restrict__ A, const u16* __restrict__ B,
             void* __restrict__ C, const void* __restrict__ E,
             int M, int N, int K, int ldc, int coff)
{
    __shared__ __align__(16) u16 As[128 * 64];
    __shared__ __align__(16) u16 Bs[128 * 64];

    const int tid  = threadIdx.x;
    const int lane = tid & 63;
    const int wid  = tid >> 6;
    const int m0 = blockIdx.y * 128;
    const int n0 = blockIdx.x * 128;
    const int wm = (wid >> 1) * 64;
    const int wn = (wid & 1) * 64;
    const int l31 = lane & 31, kg = lane >> 5;

    f32x16 acc[2][2];
#pragma unroll
    for (int i = 0; i < 2; i++)
#pragma unroll
        for (int j = 0; j < 2; j++)
#pragma unroll
            for (int r = 0; r < 16; r++) acc[i][j][r] = 0.f;

    const u16* Ag[4]; const u16* Bg[4]; u16* Al[4]; u16* Bl[4];
#pragma unroll
    for (int j = 0; j < 4; j++) {
        const int q = j * 256 + tid;
        const int r = q >> 3, s = q & 7, c = s ^ (r & 7);
        Ag[j] = A + (size_t)(m0 + r) * K + c * 8;
        Bg[j] = B + (size_t)(n0 + r) * K + c * 8;
        Al[j] = As + q * 8;
        Bl[j] = Bs + q * 8;
    }

    int arow[2], brow[2];
#pragma unroll
    for (int i = 0; i < 2; i++) { arow[i] = wm + i * 32 + l31; }
#pragma unroll
    for (int j = 0; j < 2; j++) { brow[j] = wn + j * 32 + l31; }

    for (int kt = 0; kt < K; kt += 64) {
        __syncthreads();
#pragma unroll
        for (int j = 0; j < 4; j++) {
            gl_lds16(Ag[j] + kt, Al[j]);
            gl_lds16(Bg[j] + kt, Bl[j]);
        }
        __syncthreads();

#pragma unroll
        for (int s = 0; s < 4; s++) {
            const int ch = s * 2 + kg;
            bf16x8 af[2], bf[2];
#pragma unroll
            for (int i = 0; i < 2; i++)
                af[i] = *(const bf16x8*)(
                    &As[arow[i] * 64 + ((ch ^ (arow[i] & 7)) * 8)]);
#pragma unroll
            for (int j = 0; j < 2; j++)
                bf[j] = *(const bf16x8*)(
                    &Bs[brow[j] * 64 + ((ch ^ (brow[j] & 7)) * 8)]);
#pragma unroll
            for (int i = 0; i < 2; i++)
#pragma unroll
                for (int j = 0; j < 2; j++)
                    acc[i][j] = __builtin_amdgcn_mfma_f32_32x32x16_bf16(
                        af[i], bf[j], acc[i][j], 0, 0, 0);
        }
    }

#pragma unroll
    for (int i = 0; i < 2; i++) {
#pragma unroll
        for (int r = 0; r < 16; r++) {
            const int row = m0 + wm + i * 32 + (r & 3) + 8 * (r >> 2) + 4 * kg;
#pragma unroll
            for (int j = 0; j < 2; j++) {
                const int col = n0 + wn + j * 32 + l31;
                const size_t idx = (size_t)row * ldc + coff + col;
                const float v = acc[i][j][r];
                if (EPI == 0) {
                    ((u16*)C)[idx] = f2b(v);
                } else {
                    ((float*)C)[idx] = v + ((const float*)E)[idx];
                }
            }
        }
    }
}

// ---------------------------------------------------------------------------
// Shared 8-phase scheduling macros (validated in gemm8_mlp, R0/R1 passes).
// ---------------------------------------------------------------------------
#define MIDBAR \
    __builtin_amdgcn_s_barrier(); \
    asm volatile("s_waitcnt lgkmcnt(0)" ::: "memory"); \
    __builtin_amdgcn_sched_barrier(0);

#define PBAR \
    __builtin_amdgcn_s_barrier(); \
    asm volatile("" ::: "memory"); \
    __builtin_amdgcn_sched_barrier(0);

#define VMBARN(n) \
    asm volatile("s_waitcnt vmcnt(" #n ")" ::: "memory"); \
    __builtin_amdgcn_s_barrier(); \
    asm volatile("" ::: "memory"); \
    __builtin_amdgcn_sched_barrier(0);

// ---------------------------------------------------------------------------
// 8-phase 256x256 MLP GEMM (gate+up combined, N=8192 interleaved), BK=64,
// 512 thr = 8 waves (2M x 4N), per-wave 128x64 out, mfma 16x16x32.
// LDS 128 KiB: As/Bs = 2 dbuf x 2 half(128 rows) x [128][64] XOR-swizzled.
// Counted vmcnt (4), never 0 in steady state.  Epilogue: silu(up)*gate.
// ---------------------------------------------------------------------------
#define LDA(bufi, mh) { \
    const u16* _ab = Ab##bufi + (mh) * 4096; \
    _Pragma("unroll") \
    for (int _m = 0; _m < 4; ++_m) { \
        Aq[_m][0] = *(const bf16x8*)(_ab + _m * 1024 + axor0); \
        Aq[_m][1] = *(const bf16x8*)(_ab + _m * 1024 + axor1); \
    } }

#define LDB(bufi, nh) { \
    const u16* _bb = Bb##bufi + (nh) * 2048; \
    _Pragma("unroll") \
    for (int _n = 0; _n < 2; ++_n) { \
        Bq[nh][_n][0] = *(const bf16x8*)(_bb + _n * 1024 + axor0); \
        Bq[nh][_n][1] = *(const bf16x8*)(_bb + _n * 1024 + axor1); \
    } }

#define MM(mh, nh) \
    __builtin_amdgcn_s_setprio(1); \
    { _Pragma("unroll") \
      for (int _m = 0; _m < 4; ++_m) { \
        _Pragma("unroll") \
        for (int _n = 0; _n < 2; ++_n) { \
            acc[(mh)*4+_m][(nh)*2+_n] = __builtin_amdgcn_mfma_f32_16x16x32_bf16( \
                Aq[_m][0], Bq[nh][_n][0], acc[(mh)*4+_m][(nh)*2+_n], 0, 0, 0); \
            acc[(mh)*4+_m][(nh)*2+_n] = __builtin_amdgcn_mfma_f32_16x16x32_bf16( \
                Aq[_m][1], Bq[nh][_n][1], acc[(mh)*4+_m][(nh)*2+_n], 0, 0, 0); \
        } } } \
    __builtin_amdgcn_s_setprio(0);

#define STAGE_A(tile, half) { \
    const u16* _s = pA0 + (size_t)(half) * 131072 + (size_t)(tile) * 64; \
    u16* _d = lA0 + ((tile) & 1) * 16384 + (half) * 8192; \
    gl_lds16(_s, _d); \
    gl_lds16(_s + 65536, _d + 4096); }

#define STAGE_B(tile, half) { \
    const u16* _s = pB0 + (size_t)(half) * 131072 + (size_t)(tile) * 64; \
    u16* _d = lB0 + ((tile) & 1) * 16384 + (half) * 8192; \
    gl_lds16(_s, _d); \
    gl_lds16(_s + 65536, _d + 4096); }

__global__ __launch_bounds__(512, 2)
void gemm8_mlp(const u16* __restrict__ A, const u16* __restrict__ Bc,
               u16* __restrict__ H)
{
    __shared__ __align__(16) u16 As[32768];   // 2 buf x 2 half x 128 x 64
    __shared__ __align__(16) u16 Bs[32768];

    const int tid = threadIdx.x, lane = tid & 63, wid = tid >> 6;
    const int wr = wid >> 2, wc = wid & 3;
    const int r15 = lane & 15, ks = lane >> 4;
    const int m0 = blockIdx.y * 256, n0 = blockIdx.x * 256;

    // per-lane swizzled frag offsets: slot = (kf*4+ks) ^ (row&7)
    const int axor0 = ((ks) ^ (r15 & 7)) * 8;
    const int axor1 = ((4 + ks) ^ (r15 & 7)) * 8;
    const u16* Ab0 = As + wr * 8192 + r15 * 64;
    const u16* Ab1 = As + 16384 + wr * 8192 + r15 * 64;
    const u16* Bb0 = Bs + (wc >> 1) * 8192 + (wc & 1) * 4096 + r15 * 64;
    const u16* Bb1 = Bs + 16384 + (wc >> 1) * 8192 + (wc & 1) * 4096 + r15 * 64;

    // staging: thread t covers chunk q=t (rows 0..63) and q=512+t (rows 64..127)
    const int r0 = tid >> 3, c0 = (tid & 7) ^ (r0 & 7);
    const u16* pA0 = A  + (size_t)(m0 + r0) * 1024 + c0 * 8;
    const u16* pB0 = Bc + (size_t)(n0 + r0) * 1024 + c0 * 8;
    u16* lA0 = As + tid * 8;
    u16* lB0 = Bs + tid * 8;

    f32x4 acc[8][4];
#pragma unroll
    for (int m = 0; m < 8; ++m)
#pragma unroll
        for (int n = 0; n < 4; ++n)
            acc[m][n] = (f32x4){0.f, 0.f, 0.f, 0.f};

    bf16x8 Aq[4][2], Bq[2][2][2];

    // ---- prologue: tile0 (all 4 halves) + tile1 (B0,B1); keep tile1's 2 in flight
    STAGE_A(0, 0); STAGE_A(0, 1);
    STAGE_B(0, 0); STAGE_B(0, 1);
    STAGE_B(1, 0); STAGE_B(1, 1);
    asm volatile("s_waitcnt vmcnt(4)" ::: "memory");
    __builtin_amdgcn_s_barrier();
    asm volatile("" ::: "memory");
    __builtin_amdgcn_sched_barrier(0);

    for (int i = 0; i < 8; ++i) {
        const int t1 = 2 * i + 1;
        const int t2 = 2 * i + 2;
        const int t3 = 2 * i + 3;
        const bool st = (i < 7);      // t2<16 and t3<16

        // ---- phase 1: quad(0,0) of tile 2i (buf0)
        LDA(0, 0); LDB(0, 0);
        STAGE_A(t1, 0);
        MIDBAR; MM(0, 0); PBAR;
        // ---- phase 2: quad(0,1)
        LDB(0, 1);
        STAGE_A(t1, 1);
        MIDBAR; MM(0, 1); PBAR;
        // ---- phase 3: quad(1,1)
        LDA(0, 1);
        if (st) STAGE_B(t2, 0);
        MIDBAR; MM(1, 1); PBAR;
        // ---- phase 4: quad(1,0); retire tile 2i+1 (needed p5-8)
        if (st) STAGE_B(t2, 1);
        MIDBAR; MM(1, 0);
        if (i == 7) { VMBARN(0); } else { VMBARN(4); }

        // ---- phase 5: quad(0,0) of tile 2i+1 (buf1)
        LDA(1, 0); LDB(1, 0);
        if (st) STAGE_A(t2, 0);
        MIDBAR; MM(0, 0); PBAR;
        // ---- phase 6: quad(0,1)
        LDB(1, 1);
        if (st) STAGE_A(t2, 1);
        MIDBAR; MM(0, 1); PBAR;
        // ---- phase 7: quad(1,1)
        LDA(1, 1);
        if (st) STAGE_B(t3, 0);
        MIDBAR; MM(1, 1); PBAR;
        // ---- phase 8: quad(1,0); retire tile 2i+2 (needed next p1-4)
        if (st) STAGE_B(t3, 1);
        MIDBAR; MM(1, 0);
        VMBARN(4);
    }

    // ---- epilogue: silu(up)*gate, register-local pairs (n=2p gate, 2p+1 up)
    const int orow0 = m0 + wr * 128;
    const int ocol0 = (n0 >> 1) + wc * 32;
#pragma unroll
    for (int m = 0; m < 8; ++m) {
#pragma unroll
        for (int p = 0; p < 2; ++p) {
#pragma unroll
            for (int r = 0; r < 4; ++r) {
                const int row = orow0 + m * 16 + ks * 4 + r;
                const int col = ocol0 + p * 16 + r15;
                const float g = acc[m][2 * p][r];
                const float u = acc[m][2 * p + 1][r];
                H[(size_t)row * 4096 + col] = f2b(u / (1.f + __expf(-u)) * g);
            }
        }
    }
}

// ---------------------------------------------------------------------------
// RMSNorm: fp32 in, fp32 weight, bf16 out. One block/token, 256 thr x 4 elems
// ---------------------------------------------------------------------------
__global__ __launch_bounds__(256)
void rmsnorm_k(const float* __restrict__ xin, const float* __restrict__ w,
               u16* __restrict__ o)
{
    const int t = blockIdx.x;
    const int tid = threadIdx.x;
    float4 xv = ((const float4*)xin)[(size_t)t * 256 + tid];
    float ss = xv.x * xv.x + xv.y * xv.y + xv.z * xv.z + xv.w * xv.w;
#pragma unroll
    for (int off = 32; off > 0; off >>= 1) ss += __shfl_down(ss, off);
    __shared__ float red[4];
    const int lane = tid & 63, wv_ = tid >> 6;
    if (lane == 0) red[wv_] = ss;
    __syncthreads();
    const float tot = red[0] + red[1] + red[2] + red[3];
    const float inv = rsqrtf(tot * (1.f / 1024.f) + 1e-5f);
    float4 ww = ((const float4*)w)[tid];
    ushort4 ov;
    ov.x = f2b(xv.x * inv * ww.x);
    ov.y = f2b(xv.y * inv * ww.y);
    ov.z = f2b(xv.z * inv * ww.z);
    ov.w = f2b(xv.w * inv * ww.w);
    ((ushort4*)o)[(size_t)t * 256 + tid] = ov;
}

// ---------------------------------------------------------------------------
// RoPE tables + apply. Q scaled by 0.125*log2(e) so attn can use exp2.
// ---------------------------------------------------------------------------
#define QSCALE 0.18033688011112042f   // (1/sqrt(64)) * log2(e)

__global__ void rope_tab(float* __restrict__ cs, float* __restrict__ sn)
{
    const int s = blockIdx.x;
    const int i = threadIdx.x;
    const double inv = exp(-((double)(2 * i) / 64.0) * log(10000.0));
    const double ang = (double)s * inv;
    cs[s * 32 + i] = (float)cos(ang);
    sn[s * 32 + i] = (float)sin(ang);
}

__global__ __launch_bounds__(256)
void rope_apply(u16* __restrict__ qkv, const float* __restrict__ cs,
                const float* __restrict__ sn)
{
    const int t = blockIdx.x;
    const int s = t & (SEQ - 1);
    u16* row = qkv + (size_t)t * 3072;
    __shared__ float c_s[32], s_s[32];
    if (threadIdx.x < 32) {
        c_s[threadIdx.x] = cs[s * 32 + threadIdx.x];
        s_s[threadIdx.x] = sn[s * 32 + threadIdx.x];
    }
    __syncthreads();
#pragma unroll
    for (int rr = 0; rr < 2; rr++) {
        const int item = rr * 256 + threadIdx.x;
        const int hh = item >> 5, i = item & 31;
        const int f = hh * 64 + 2 * i;
        const float c = c_s[i], sv = s_s[i];
        float xe = b2f(row[f]), xo = b2f(row[f + 1]);
        row[f]     = f2b((xe * c - xo * sv) * QSCALE);   // Q: fold scale+log2e
        row[f + 1] = f2b((xo * c + xe * sv) * QSCALE);
        xe = b2f(row[1024 + f]); xo = b2f(row[1024 + f + 1]);
        row[1024 + f]     = f2b(xe * c - xo * sv);       // K: unscaled
        row[1024 + f + 1] = f2b(xo * c + xe * sv);
    }
}

// ---------------------------------------------------------------------------
// V pre-transpose: vt[bh][d][s] from qkv v-columns. LDS-tiled, one-shot.
// ---------------------------------------------------------------------------
__global__ __launch_bounds__(256)
void vtrans(const u16* __restrict__ qkv, u16* __restrict__ vt)
{
    __shared__ u16 Ld[64 * 264];
    const int bh = blockIdx.x, st = blockIdx.y;
    const int b = bh >> 4, h = bh & 15;
    const int tid = threadIdx.x;
    const u16* src = qkv + ((size_t)(b * SEQ + st * 256 + tid)) * 3072 + 2048 + h * 64;
    uint4 v[8];
#pragma unroll
    for (int c = 0; c < 8; c++) v[c] = *(const uint4*)(src + c * 8);
#pragma unroll
    for (int c = 0; c < 8; c++) {
        const u16* pv = (const u16*)&v[c];
#pragma unroll
        for (int j = 0; j < 8; j++)
            Ld[(c * 8 + j) * 264 + tid] = pv[j];
    }
    __syncthreads();
    u16* dst = vt + (size_t)bh * (64 * SEQ) + st * 256;
#pragma unroll
    for (int cc = 0; cc < 8; cc++) {
        const int c = cc * 256 + tid;
        const int d = c >> 5, t8 = (c & 31) * 8;
        *(uint4*)(dst + (size_t)d * SEQ + t8) = *(const uint4*)(&Ld[d * 264 + t8]);
    }
}

// ---------------------------------------------------------------------------
// Flash attention (causal), static-max softmax: P = exp2(s) directly (Q
// pre-scaled by 0.125*log2e). l via ones-column MFMA. Block = 512 thr,
// 2 q-tiles of 128 rows (qy, 15-qy).
// R4: double-buffered K/V staging via global_load_lds (source-chunk XOR
// swizzle, linear LDS dest), issue-early/wait-late, ONE raw barrier per
// kv-tile (no full vmcnt drain mid-pipeline). K/V [2][64][64] linear;
// read chunk q of row r at LDS chunk q^(r&7).
// ---------------------------------------------------------------------------
__global__ __launch_bounds__(512)
void attn(const u16* __restrict__ qkv, const u16* __restrict__ vt,
          u16* __restrict__ ao)
{
    __shared__ __align__(16) u16 Ks[2][64 * 64];   // 16 KB
    __shared__ __align__(16) u16 Vs[2][64 * 64];   // 16 KB
    __shared__ __align__(16) u16 Ps[8][16 * 72];   // 18 KB

    const int bh = blockIdx.x;
    const int qy = blockIdx.y;                 // 0..7
    const int b = bh >> 4, h = bh & 15;
    const int tid = threadIdx.x, lane = tid & 63, wid = tid >> 6;
    const int am = lane & 15, grp = lane >> 4;
    const size_t tok0 = (size_t)b * SEQ;
    const u16* qbase = qkv + tok0 * 3072 + h * 64;
    const u16* kbase = qbase + 1024;
    const u16* vtg = vt + (size_t)bh * (64 * SEQ);

    union { uint4 u; bf16x8 b; } onesu;
    onesu.u = (uint4){0x3f803f80u, 0x3f803f80u, 0x3f803f80u, 0x3f803f80u};
    const bf16x8 ones = onesu.b;

    // staging geometry: thread t covers row=t>>3, chunk c=t&7; source chunk
    // is XOR-swizzled (c ^ (row&7)) so that a linear LDS write gives the
    // swizzled layout (rule #21: swizzle source + read, keep dest linear).
    const int srow = tid >> 3;
    const int scsw = ((tid & 7) ^ (srow & 7)) * 8;
    const u16* ksrc = kbase + (size_t)srow * 3072 + scsw;
    const u16* vsrc = vtg + (size_t)srow * SEQ + scsw;
    u16* kdst[2] = { &Ks[0][tid * 8], &Ks[1][tid * 8] };
    u16* vdst[2] = { &Vs[0][tid * 8], &Vs[1][tid * 8] };

#pragma unroll
    for (int tile = 0; tile < 2; tile++) {
        const int yt = tile == 0 ? qy : 15 - qy;
        const int qrow0 = yt * 128 + wid * 16;

        bf16x8 qf[2];
        {
            const u16* qp = qbase + (size_t)(qrow0 + am) * 3072 + grp * 8;
            qf[0] = *(const bf16x8*)(qp);
            qf[1] = *(const bf16x8*)(qp + 32);
        }

        f32x4 O[4], Ol;
#pragma unroll
        for (int j = 0; j < 4; j++) O[j] = (f32x4){0.f, 0.f, 0.f, 0.f};
        Ol = (f32x4){0.f, 0.f, 0.f, 0.f};

        const int ktend = yt * 128 + 64;       // last kv-tile start

        // ---- prologue: stage kv-tile 0 into buf 0
        gl_lds16(ksrc, kdst[0]);
        gl_lds16(vsrc, vdst[0]);
        asm volatile("s_waitcnt vmcnt(0)" ::: "memory");
        __builtin_amdgcn_s_barrier();
        asm volatile("" ::: "memory");
        __builtin_amdgcn_sched_barrier(0);

        int buf = 0;
        for (int kt = 0; kt <= ktend; kt += 64) {
            // ---- issue next tile's stage early (hidden under compute)
            if (kt + 64 <= ktend) {
                gl_lds16(ksrc + (size_t)(kt + 64) * 3072, kdst[buf ^ 1]);
                gl_lds16(vsrc + (kt + 64), vdst[buf ^ 1]);
            }

            if (kt <= qrow0 + 15) {            // not fully masked for this wave
                const u16* kbuf = &Ks[0][0] + buf * 4096;
                const u16* vbuf = &Vs[0][0] + buf * 4096;

                // ---- QK^T (log2 units)
                f32x4 st[4];
#pragma unroll
                for (int kk = 0; kk < 4; kk++) {
                    const int rk = kk * 16 + am;
                    bf16x8 k0 = *(const bf16x8*)(
                        &kbuf[rk * 64 + ((grp ^ (rk & 7)) * 8)]);
                    bf16x8 k1 = *(const bf16x8*)(
                        &kbuf[rk * 64 + (((grp + 4) ^ (rk & 7)) * 8)]);
                    f32x4 s = (f32x4){0.f, 0.f, 0.f, 0.f};
                    s = __builtin_amdgcn_mfma_f32_16x16x32_bf16(qf[0], k0, s, 0, 0, 0);
                    s = __builtin_amdgcn_mfma_f32_16x16x32_bf16(qf[1], k1, s, 0, 0, 0);
                    st[kk] = s;
                }
                if (kt + 63 > qrow0) {         // diagonal: apply causal mask
#pragma unroll
                    for (int kk = 0; kk < 4; kk++) {
                        const int kg2 = kt + kk * 16 + am;
#pragma unroll
                        for (int r = 0; r < 4; r++) {
                            const int qg = qrow0 + grp * 4 + r;
                            if (kg2 > qg) st[kk][r] = -1e30f;
                        }
                    }
                }
                // ---- static-max softmax: P = exp2(s), masked -> 0
#pragma unroll
                for (int kk = 0; kk < 4; kk++)
#pragma unroll
                    for (int r = 0; r < 4; r++)
                        st[kk][r] = exp2f(st[kk][r]);

                // ---- P: C-layout -> per-wave LDS -> A-layout
                u16* pw = &Ps[wid][0];
#pragma unroll
                for (int kk = 0; kk < 4; kk++)
#pragma unroll
                    for (int r = 0; r < 4; r++)
                        pw[(grp * 4 + r) * 72 + kk * 16 + am] = f2b_trunc(st[kk][r]);
                asm volatile("s_waitcnt lgkmcnt(0)" ::: "memory");

                // ---- PV + ones-column l accumulation
#pragma unroll
                for (int hh = 0; hh < 2; hh++) {
                    bf16x8 pf = *(const bf16x8*)(&pw[am * 72 + hh * 32 + grp * 8]);
                    Ol = __builtin_amdgcn_mfma_f32_16x16x32_bf16(pf, ones, Ol, 0, 0, 0);
#pragma unroll
                    for (int jt = 0; jt < 4; jt++) {
                        const int rv = jt * 16 + am;
                        bf16x8 vf = *(const bf16x8*)(
                            &vbuf[rv * 64 + (((hh * 4 + grp) ^ (rv & 7)) * 8)]);
                        O[jt] = __builtin_amdgcn_mfma_f32_16x16x32_bf16(
                            pf, vf, O[jt], 0, 0, 0);
                    }
                }
            }

            // ---- tile boundary: own stage loads landed (issued one full
            // compute phase ago), then collective barrier. Never drains the
            // LDS pipe or other waves' loads mid-flight beyond necessity.
            asm volatile("s_waitcnt vmcnt(0)" ::: "memory");
            __builtin_amdgcn_s_barrier();
            asm volatile("" ::: "memory");
            __builtin_amdgcn_sched_barrier(0);
            buf ^= 1;
        }

        // ---- epilogue for this q-tile
        u16* aorow = ao + (tok0 + qrow0) * 1024 + h * 64;
#pragma unroll
        for (int r = 0; r < 4; r++) {
            const int q = grp * 4 + r;
            const float invl = 1.f / Ol[r];
#pragma unroll
            for (int jt = 0; jt < 4; jt++)
                aorow[(size_t)q * 1024 + jt * 16 + am] = f2b(O[jt][r] * invl);
        }
    }
}

// ---------------------------------------------------------------------------
extern "C" void kernel_launch(void* const* d_in, const int* in_sizes, int n_in,
                              void* d_out, int out_size, void* d_ws, size_t ws_size,
                              hipStream_t stream)
{
    (void)in_sizes; (void)n_in; (void)out_size; (void)ws_size;
    const float* x     = (const float*)d_in[0];
    const float* wq    = (const float*)d_in[1];
    const float* wk    = (const float*)d_in[2];
    const float* wv    = (const float*)d_in[3];
    const float* wo    = (const float*)d_in[4];
    const float* ln1   = (const float*)d_in[5];
    const float* ln2   = (const float*)d_in[6];
    const float* wup   = (const float*)d_in[7];
    const float* wgate = (const float*)d_in[8];
    const float* wdown = (const float*)d_in[9];
    float* out = (float*)d_out;
    char* ws = (char*)d_ws;
    const size_t MB = 1024 * 1024;

    u16*   xn   = (u16*)(ws);
    u16*   ao   = (u16*)(ws);
    u16*   qkv  = (u16*)(ws + 16 * MB);
    u16*   hbuf = (u16*)(ws + 16 * MB);
    u16*   vtb  = (u16*)(ws + 64 * MB);
    float* x1   = (float*)(ws + 80 * MB);
    u16*   bwq  = (u16*)(ws + 112 * MB);
    u16*   bwk  = (u16*)(ws + 114 * MB);
    u16*   bwv  = (u16*)(ws + 116 * MB);
    u16*   bwo  = (u16*)(ws + 118 * MB);
    u16*   bwmu = (u16*)(ws + 120 * MB);             // gate/up interleaved, 16MB
    u16*   bwdn = (u16*)(ws + 136 * MB);
    float* cst  = (float*)(ws + 144 * MB);
    float* snt  = (float*)(ws + 144 * MB + 262144);

    cvt_all<<<16384, 256, 0, stream>>>(wq, wk, wv, wo, wup, wgate, wdown,
                                       bwq, bwk, bwv, bwo, bwmu, bwdn);

    rope_tab<<<SEQ, 32, 0, stream>>>(cst, snt);
    rmsnorm_k<<<NTOK, 256, 0, stream>>>(x, ln1, xn);
    gemm_bt<0><<<dim3(24, 64), 256, 0, stream>>>(xn, bwq, qkv, nullptr, NTOK, 3072, 1024, 3072, 0);
    rope_apply<<<NTOK, 256, 0, stream>>>(qkv, cst, snt);
    vtrans<<<dim3(64, 8), 256, 0, stream>>>(qkv, vtb);
    attn<<<dim3(64, 8), 512, 0, stream>>>(qkv, vtb, ao);
    gemm_bt<1><<<dim3(8, 64), 256, 0, stream>>>(ao, bwo, x1, x, NTOK, 1024, 1024, 1024, 0);
    rmsnorm_k<<<NTOK, 256, 0, stream>>>(x1, ln2, xn);
    gemm8_mlp<<<dim3(32, 32), 512, 0, stream>>>(xn, bwmu, hbuf);
    gemm_bt<1><<<dim3(8, 64), 256, 0, stream>>>(hbuf, bwdn, out, x1, NTOK, 1024, 4096, 1024, 0);
}

// Round 5
// 571.442 us; speedup vs baseline: 1.0273x; 1.0273x over previous
//
#include <hip/hip_runtime.h>
#include <stdint.h>

#define SEQ   2048
#define NTOK  8192   // 4 * 2048

typedef unsigned short u16;
typedef __bf16 bf16x8 __attribute__((ext_vector_type(8)));
typedef float  f32x4  __attribute__((ext_vector_type(4)));
typedef float  f32x16 __attribute__((ext_vector_type(16)));

__device__ __forceinline__ float b2f(u16 b) {
    union { unsigned u; float f; } v; v.u = ((unsigned)b) << 16; return v.f;
}
__device__ __forceinline__ u16 f2b(float f) {
    union { float f; unsigned u; } v; v.f = f;
    unsigned r = (v.u + 0x7fffu + ((v.u >> 16) & 1u)) >> 16;
    return (u16)r;
}
__device__ __forceinline__ u16 f2b_trunc(float f) {   // cheap, P >= 0
    union { float f; unsigned u; } v; v.f = f;
    return (u16)(v.u >> 16);
}

__device__ __forceinline__ void gl_lds16(const void* g, void* l) {
    __builtin_amdgcn_global_load_lds(
        (const __attribute__((address_space(1))) void*)g,
        (__attribute__((address_space(3))) void*)l,
        16, 0, 0);
}

// ---------------------------------------------------------------------------
// fp32 -> bf16 conversion, all 7 weight matrices in ONE dispatch.
// gate/up are interleaved into ONE combined matrix dmu[8192][1024]:
//   rows [32q..32q+16) = gate rows [16q..16q+16)
//   rows [32q+16..32q+32) = up rows [16q..16q+16)
// so the 8-phase MLP GEMM can pair gate/up register-locally (16-col frags).
// ---------------------------------------------------------------------------
__global__ __launch_bounds__(256)
void cvt_all(const float* __restrict__ wq, const float* __restrict__ wk,
             const float* __restrict__ wv, const float* __restrict__ wo,
             const float* __restrict__ wup, const float* __restrict__ wgt,
             const float* __restrict__ wdn,
             u16* __restrict__ dq, u16* __restrict__ dk, u16* __restrict__ dv,
             u16* __restrict__ dw, u16* __restrict__ dmu, u16* __restrict__ dd)
{
    const int bid = blockIdx.x;
    const float* s; u16* d; int osrc, odst;
    if (bid < 4096) {
        const int which = bid >> 10;
        osrc = odst = (bid & 1023) * 256 + threadIdx.x;
        s = which == 0 ? wq : which == 1 ? wk : which == 2 ? wv : wo;
        d = which == 0 ? dq : which == 1 ? dk : which == 2 ? dv : dw;
    } else {
        const int which = (bid - 4096) >> 12;     // 0=up 1=gate 2=down
        const int o = ((bid - 4096) & 4095) * 256 + threadIdx.x;
        osrc = o;
        if (which == 2) { s = wdn; d = dd; odst = o; }
        else {
            s = which == 0 ? wup : wgt;
            d = dmu;
            const int row = o >> 8;               // 256 float4 per 1024-col row
            const int rowp = ((row >> 4) << 5) + (row & 15) + (which == 0 ? 16 : 0);
            odst = rowp * 256 + (o & 255);
        }
    }
    float4 v = ((const float4*)s)[osrc];
    ushort4 ov;
    ov.x = f2b(v.x); ov.y = f2b(v.y); ov.z = f2b(v.z); ov.w = f2b(v.w);
    ((ushort4*)d)[odst] = ov;
}

// ---------------------------------------------------------------------------
// GEMM: C[M][N] = A[M][K] * B[N][K]^T   (bf16 in, fp32 accum)
// 128x128 tile, BK=64, XOR-swizzled LDS, mfma 32x32x16.
// EPI 0: bf16 C[idx] = acc
// EPI 1: f32  C[idx] = acc + E_f32[idx]          (fused residual, fp32 out)
// ---------------------------------------------------------------------------
template<int EPI>
__global__ __launch_bounds__(256)
void gemm_bt(const u16* __restrict__ A, const u16* __restrict__ B,
             void* __restrict__ C, const void* __restrict__ E,
             int M, int N, int K, int ldc, int coff)
{
    __shared__ __align__(16) u16 As[128 * 64];
    __shared__ __align__(16) u16 Bs[128 * 64];

    const int tid  = threadIdx.x;
    const int lane = tid & 63;
    const int wid  = tid >> 6;
    const int m0 = blockIdx.y * 128;
    const int n0 = blockIdx.x * 128;
    const int wm = (wid >> 1) * 64;
    const int wn = (wid & 1) * 64;
    const int l31 = lane & 31, kg = lane >> 5;

    f32x16 acc[2][2];
#pragma unroll
    for (int i = 0; i < 2; i++)
#pragma unroll
        for (int j = 0; j < 2; j++)
#pragma unroll
            for (int r = 0; r < 16; r++) acc[i][j][r] = 0.f;

    const u16* Ag[4]; const u16* Bg[4]; u16* Al[4]; u16* Bl[4];
#pragma unroll
    for (int j = 0; j < 4; j++) {
        const int q = j * 256 + tid;
        const int r = q >> 3, s = q & 7, c = s ^ (r & 7);
        Ag[j] = A + (size_t)(m0 + r) * K + c * 8;
        Bg[j] = B + (size_t)(n0 + r) * K + c * 8;
        Al[j] = As + q * 8;
        Bl[j] = Bs + q * 8;
    }

    int arow[2], brow[2];
#pragma unroll
    for (int i = 0; i < 2; i++) { arow[i] = wm + i * 32 + l31; }
#pragma unroll
    for (int j = 0; j < 2; j++) { brow[j] = wn + j * 32 + l31; }

    for (int kt = 0; kt < K; kt += 64) {
        __syncthreads();
#pragma unroll
        for (int j = 0; j < 4; j++) {
            gl_lds16(Ag[j] + kt, Al[j]);
            gl_lds16(Bg[j] + kt, Bl[j]);
        }
        __syncthreads();

#pragma unroll
        for (int s = 0; s < 4; s++) {
            const int ch = s * 2 + kg;
            bf16x8 af[2], bf[2];
#pragma unroll
            for (int i = 0; i < 2; i++)
                af[i] = *(const bf16x8*)(
                    &As[arow[i] * 64 + ((ch ^ (arow[i] & 7)) * 8)]);
#pragma unroll
            for (int j = 0; j < 2; j++)
                bf[j] = *(const bf16x8*)(
                    &Bs[brow[j] * 64 + ((ch ^ (brow[j] & 7)) * 8)]);
#pragma unroll
            for (int i = 0; i < 2; i++)
#pragma unroll
                for (int j = 0; j < 2; j++)
                    acc[i][j] = __builtin_amdgcn_mfma_f32_32x32x16_bf16(
                        af[i], bf[j], acc[i][j], 0, 0, 0);
        }
    }

#pragma unroll
    for (int i = 0; i < 2; i++) {
#pragma unroll
        for (int r = 0; r < 16; r++) {
            const int row = m0 + wm + i * 32 + (r & 3) + 8 * (r >> 2) + 4 * kg;
#pragma unroll
            for (int j = 0; j < 2; j++) {
                const int col = n0 + wn + j * 32 + l31;
                const size_t idx = (size_t)row * ldc + coff + col;
                const float v = acc[i][j][r];
                if (EPI == 0) {
                    ((u16*)C)[idx] = f2b(v);
                } else {
                    ((float*)C)[idx] = v + ((const float*)E)[idx];
                }
            }
        }
    }
}

// ---------------------------------------------------------------------------
// Shared 8-phase scheduling macros (validated in gemm8_mlp, R0/R1 passes).
// ---------------------------------------------------------------------------
#define MIDBAR \
    __builtin_amdgcn_s_barrier(); \
    asm volatile("s_waitcnt lgkmcnt(0)" ::: "memory"); \
    __builtin_amdgcn_sched_barrier(0);

#define PBAR \
    __builtin_amdgcn_s_barrier(); \
    asm volatile("" ::: "memory"); \
    __builtin_amdgcn_sched_barrier(0);

#define VMBARN(n) \
    asm volatile("s_waitcnt vmcnt(" #n ")" ::: "memory"); \
    __builtin_amdgcn_s_barrier(); \
    asm volatile("" ::: "memory"); \
    __builtin_amdgcn_sched_barrier(0);

// ---------------------------------------------------------------------------
// 8-phase 256x256 MLP GEMM (gate+up combined, N=8192 interleaved), BK=64,
// 512 thr = 8 waves (2M x 4N), per-wave 128x64 out, mfma 16x16x32.
// LDS 128 KiB: As/Bs = 2 dbuf x 2 half(128 rows) x [128][64] XOR-swizzled.
// Counted vmcnt (4), never 0 in steady state.  Epilogue: silu(up)*gate.
// ---------------------------------------------------------------------------
#define LDA(bufi, mh) { \
    const u16* _ab = Ab##bufi + (mh) * 4096; \
    _Pragma("unroll") \
    for (int _m = 0; _m < 4; ++_m) { \
        Aq[_m][0] = *(const bf16x8*)(_ab + _m * 1024 + axor0); \
        Aq[_m][1] = *(const bf16x8*)(_ab + _m * 1024 + axor1); \
    } }

#define LDB(bufi, nh) { \
    const u16* _bb = Bb##bufi + (nh) * 2048; \
    _Pragma("unroll") \
    for (int _n = 0; _n < 2; ++_n) { \
        Bq[nh][_n][0] = *(const bf16x8*)(_bb + _n * 1024 + axor0); \
        Bq[nh][_n][1] = *(const bf16x8*)(_bb + _n * 1024 + axor1); \
    } }

#define MM(mh, nh) \
    __builtin_amdgcn_s_setprio(1); \
    { _Pragma("unroll") \
      for (int _m = 0; _m < 4; ++_m) { \
        _Pragma("unroll") \
        for (int _n = 0; _n < 2; ++_n) { \
            acc[(mh)*4+_m][(nh)*2+_n] = __builtin_amdgcn_mfma_f32_16x16x32_bf16( \
                Aq[_m][0], Bq[nh][_n][0], acc[(mh)*4+_m][(nh)*2+_n], 0, 0, 0); \
            acc[(mh)*4+_m][(nh)*2+_n] = __builtin_amdgcn_mfma_f32_16x16x32_bf16( \
                Aq[_m][1], Bq[nh][_n][1], acc[(mh)*4+_m][(nh)*2+_n], 0, 0, 0); \
        } } } \
    __builtin_amdgcn_s_setprio(0);

#define STAGE_A(tile, half) { \
    const u16* _s = pA0 + (size_t)(half) * 131072 + (size_t)(tile) * 64; \
    u16* _d = lA0 + ((tile) & 1) * 16384 + (half) * 8192; \
    gl_lds16(_s, _d); \
    gl_lds16(_s + 65536, _d + 4096); }

#define STAGE_B(tile, half) { \
    const u16* _s = pB0 + (size_t)(half) * 131072 + (size_t)(tile) * 64; \
    u16* _d = lB0 + ((tile) & 1) * 16384 + (half) * 8192; \
    gl_lds16(_s, _d); \
    gl_lds16(_s + 65536, _d + 4096); }

__global__ __launch_bounds__(512, 2)
void gemm8_mlp(const u16* __restrict__ A, const u16* __restrict__ Bc,
               u16* __restrict__ H)
{
    __shared__ __align__(16) u16 As[32768];   // 2 buf x 2 half x 128 x 64
    __shared__ __align__(16) u16 Bs[32768];

    const int tid = threadIdx.x, lane = tid & 63, wid = tid >> 6;
    const int wr = wid >> 2, wc = wid & 3;
    const int r15 = lane & 15, ks = lane >> 4;
    const int m0 = blockIdx.y * 256, n0 = blockIdx.x * 256;

    // per-lane swizzled frag offsets: slot = (kf*4+ks) ^ (row&7)
    const int axor0 = ((ks) ^ (r15 & 7)) * 8;
    const int axor1 = ((4 + ks) ^ (r15 & 7)) * 8;
    const u16* Ab0 = As + wr * 8192 + r15 * 64;
    const u16* Ab1 = As + 16384 + wr * 8192 + r15 * 64;
    const u16* Bb0 = Bs + (wc >> 1) * 8192 + (wc & 1) * 4096 + r15 * 64;
    const u16* Bb1 = Bs + 16384 + (wc >> 1) * 8192 + (wc & 1) * 4096 + r15 * 64;

    // staging: thread t covers chunk q=t (rows 0..63) and q=512+t (rows 64..127)
    const int r0 = tid >> 3, c0 = (tid & 7) ^ (r0 & 7);
    const u16* pA0 = A  + (size_t)(m0 + r0) * 1024 + c0 * 8;
    const u16* pB0 = Bc + (size_t)(n0 + r0) * 1024 + c0 * 8;
    u16* lA0 = As + tid * 8;
    u16* lB0 = Bs + tid * 8;

    f32x4 acc[8][4];
#pragma unroll
    for (int m = 0; m < 8; ++m)
#pragma unroll
        for (int n = 0; n < 4; ++n)
            acc[m][n] = (f32x4){0.f, 0.f, 0.f, 0.f};

    bf16x8 Aq[4][2], Bq[2][2][2];

    // ---- prologue: tile0 (all 4 halves) + tile1 (B0,B1); keep tile1's 2 in flight
    STAGE_A(0, 0); STAGE_A(0, 1);
    STAGE_B(0, 0); STAGE_B(0, 1);
    STAGE_B(1, 0); STAGE_B(1, 1);
    asm volatile("s_waitcnt vmcnt(4)" ::: "memory");
    __builtin_amdgcn_s_barrier();
    asm volatile("" ::: "memory");
    __builtin_amdgcn_sched_barrier(0);

    for (int i = 0; i < 8; ++i) {
        const int t1 = 2 * i + 1;
        const int t2 = 2 * i + 2;
        const int t3 = 2 * i + 3;
        const bool st = (i < 7);      // t2<16 and t3<16

        // ---- phase 1: quad(0,0) of tile 2i (buf0)
        LDA(0, 0); LDB(0, 0);
        STAGE_A(t1, 0);
        MIDBAR; MM(0, 0); PBAR;
        // ---- phase 2: quad(0,1)
        LDB(0, 1);
        STAGE_A(t1, 1);
        MIDBAR; MM(0, 1); PBAR;
        // ---- phase 3: quad(1,1)
        LDA(0, 1);
        if (st) STAGE_B(t2, 0);
        MIDBAR; MM(1, 1); PBAR;
        // ---- phase 4: quad(1,0); retire tile 2i+1 (needed p5-8)
        if (st) STAGE_B(t2, 1);
        MIDBAR; MM(1, 0);
        if (i == 7) { VMBARN(0); } else { VMBARN(4); }

        // ---- phase 5: quad(0,0) of tile 2i+1 (buf1)
        LDA(1, 0); LDB(1, 0);
        if (st) STAGE_A(t2, 0);
        MIDBAR; MM(0, 0); PBAR;
        // ---- phase 6: quad(0,1)
        LDB(1, 1);
        if (st) STAGE_A(t2, 1);
        MIDBAR; MM(0, 1); PBAR;
        // ---- phase 7: quad(1,1)
        LDA(1, 1);
        if (st) STAGE_B(t3, 0);
        MIDBAR; MM(1, 1); PBAR;
        // ---- phase 8: quad(1,0); retire tile 2i+2 (needed next p1-4)
        if (st) STAGE_B(t3, 1);
        MIDBAR; MM(1, 0);
        VMBARN(4);
    }

    // ---- epilogue: silu(up)*gate, register-local pairs (n=2p gate, 2p+1 up)
    const int orow0 = m0 + wr * 128;
    const int ocol0 = (n0 >> 1) + wc * 32;
#pragma unroll
    for (int m = 0; m < 8; ++m) {
#pragma unroll
        for (int p = 0; p < 2; ++p) {
#pragma unroll
            for (int r = 0; r < 4; ++r) {
                const int row = orow0 + m * 16 + ks * 4 + r;
                const int col = ocol0 + p * 16 + r15;
                const float g = acc[m][2 * p][r];
                const float u = acc[m][2 * p + 1][r];
                H[(size_t)row * 4096 + col] = f2b(u / (1.f + __expf(-u)) * g);
            }
        }
    }
}

// ---------------------------------------------------------------------------
// RMSNorm: fp32 in, fp32 weight, bf16 out. One block/token, 256 thr x 4 elems
// ---------------------------------------------------------------------------
__global__ __launch_bounds__(256)
void rmsnorm_k(const float* __restrict__ xin, const float* __restrict__ w,
               u16* __restrict__ o)
{
    const int t = blockIdx.x;
    const int tid = threadIdx.x;
    float4 xv = ((const float4*)xin)[(size_t)t * 256 + tid];
    float ss = xv.x * xv.x + xv.y * xv.y + xv.z * xv.z + xv.w * xv.w;
#pragma unroll
    for (int off = 32; off > 0; off >>= 1) ss += __shfl_down(ss, off);
    __shared__ float red[4];
    const int lane = tid & 63, wv_ = tid >> 6;
    if (lane == 0) red[wv_] = ss;
    __syncthreads();
    const float tot = red[0] + red[1] + red[2] + red[3];
    const float inv = rsqrtf(tot * (1.f / 1024.f) + 1e-5f);
    float4 ww = ((const float4*)w)[tid];
    ushort4 ov;
    ov.x = f2b(xv.x * inv * ww.x);
    ov.y = f2b(xv.y * inv * ww.y);
    ov.z = f2b(xv.z * inv * ww.z);
    ov.w = f2b(xv.w * inv * ww.w);
    ((ushort4*)o)[(size_t)t * 256 + tid] = ov;
}

// ---------------------------------------------------------------------------
// RoPE tables + apply. Q scaled by 0.125*log2(e) so attn can use exp2.
// ---------------------------------------------------------------------------
#define QSCALE 0.18033688011112042f   // (1/sqrt(64)) * log2(e)

__global__ void rope_tab(float* __restrict__ cs, float* __restrict__ sn)
{
    const int s = blockIdx.x;
    const int i = threadIdx.x;
    const double inv = exp(-((double)(2 * i) / 64.0) * log(10000.0));
    const double ang = (double)s * inv;
    cs[s * 32 + i] = (float)cos(ang);
    sn[s * 32 + i] = (float)sin(ang);
}

__global__ __launch_bounds__(256)
void rope_apply(u16* __restrict__ qkv, const float* __restrict__ cs,
                const float* __restrict__ sn)
{
    const int t = blockIdx.x;
    const int s = t & (SEQ - 1);
    u16* row = qkv + (size_t)t * 3072;
    __shared__ float c_s[32], s_s[32];
    if (threadIdx.x < 32) {
        c_s[threadIdx.x] = cs[s * 32 + threadIdx.x];
        s_s[threadIdx.x] = sn[s * 32 + threadIdx.x];
    }
    __syncthreads();
#pragma unroll
    for (int rr = 0; rr < 2; rr++) {
        const int item = rr * 256 + threadIdx.x;
        const int hh = item >> 5, i = item & 31;
        const int f = hh * 64 + 2 * i;
        const float c = c_s[i], sv = s_s[i];
        float xe = b2f(row[f]), xo = b2f(row[f + 1]);
        row[f]     = f2b((xe * c - xo * sv) * QSCALE);   // Q: fold scale+log2e
        row[f + 1] = f2b((xo * c + xe * sv) * QSCALE);
        xe = b2f(row[1024 + f]); xo = b2f(row[1024 + f + 1]);
        row[1024 + f]     = f2b(xe * c - xo * sv);       // K: unscaled
        row[1024 + f + 1] = f2b(xo * c + xe * sv);
    }
}

// ---------------------------------------------------------------------------
// V pre-transpose: vt[bh][d][s] from qkv v-columns. LDS-tiled, one-shot.
// ---------------------------------------------------------------------------
__global__ __launch_bounds__(256)
void vtrans(const u16* __restrict__ qkv, u16* __restrict__ vt)
{
    __shared__ u16 Ld[64 * 264];
    const int bh = blockIdx.x, st = blockIdx.y;
    const int b = bh >> 4, h = bh & 15;
    const int tid = threadIdx.x;
    const u16* src = qkv + ((size_t)(b * SEQ + st * 256 + tid)) * 3072 + 2048 + h * 64;
    uint4 v[8];
#pragma unroll
    for (int c = 0; c < 8; c++) v[c] = *(const uint4*)(src + c * 8);
#pragma unroll
    for (int c = 0; c < 8; c++) {
        const u16* pv = (const u16*)&v[c];
#pragma unroll
        for (int j = 0; j < 8; j++)
            Ld[(c * 8 + j) * 264 + tid] = pv[j];
    }
    __syncthreads();
    u16* dst = vt + (size_t)bh * (64 * SEQ) + st * 256;
#pragma unroll
    for (int cc = 0; cc < 8; cc++) {
        const int c = cc * 256 + tid;
        const int d = c >> 5, t8 = (c & 31) * 8;
        *(uint4*)(dst + (size_t)d * SEQ + t8) = *(const uint4*)(&Ld[d * 264 + t8]);
    }
}

// ---------------------------------------------------------------------------
// Flash attention (causal), static-max softmax: P = exp2(s) directly (Q
// pre-scaled by 0.125*log2e). l via ones-column MFMA. Block = 512 thr,
// 2 q-tiles of 128 rows (qy, 15-qy). K [64][72], V^T [64][72] per kv-tile.
// R5: back to the R1 staging (regular loads between barriers — compiler
// hoists the global loads into a deep prefetch automatically; the manual
// gl_lds variant measured +21 µs, R4). Added T5 setprio around MFMA
// clusters (validated +4-7% on attn, m191).
// ---------------------------------------------------------------------------
__global__ __launch_bounds__(512)
void attn(const u16* __restrict__ qkv, const u16* __restrict__ vt,
          u16* __restrict__ ao)
{
    __shared__ __align__(16) u16 Ks[64 * 72];
    __shared__ __align__(16) u16 Vt[64 * 72];
    __shared__ __align__(16) u16 Ps[8][16 * 72];

    const int bh = blockIdx.x;
    const int qy = blockIdx.y;                 // 0..7
    const int b = bh >> 4, h = bh & 15;
    const int tid = threadIdx.x, lane = tid & 63, wid = tid >> 6;
    const int am = lane & 15, grp = lane >> 4;
    const size_t tok0 = (size_t)b * SEQ;
    const u16* qbase = qkv + tok0 * 3072 + h * 64;
    const u16* kbase = qbase + 1024;
    const u16* vtg = vt + (size_t)bh * (64 * SEQ);

    union { uint4 u; bf16x8 b; } onesu;
    onesu.u = (uint4){0x3f803f80u, 0x3f803f80u, 0x3f803f80u, 0x3f803f80u};
    const bf16x8 ones = onesu.b;

    const int srow = tid >> 3, sc8 = (tid & 7) * 8;   // staging: 1 chunk each

#pragma unroll
    for (int tile = 0; tile < 2; tile++) {
        const int yt = tile == 0 ? qy : 15 - qy;
        const int qrow0 = yt * 128 + wid * 16;

        bf16x8 qf[2];
        {
            const u16* qp = qbase + (size_t)(qrow0 + am) * 3072 + grp * 8;
            qf[0] = *(const bf16x8*)(qp);
            qf[1] = *(const bf16x8*)(qp + 32);
        }

        f32x4 O[4], Ol;
#pragma unroll
        for (int j = 0; j < 4; j++) O[j] = (f32x4){0.f, 0.f, 0.f, 0.f};
        Ol = (f32x4){0.f, 0.f, 0.f, 0.f};

        const int ktend = yt * 128 + 64;       // last kv-tile start
        for (int kt = 0; kt <= ktend; kt += 64) {
            __syncthreads();
            *(uint4*)(&Ks[srow * 72 + sc8]) =
                *(const uint4*)(kbase + (size_t)(kt + srow) * 3072 + sc8);
            *(uint4*)(&Vt[srow * 72 + sc8]) =
                *(const uint4*)(vtg + (size_t)srow * SEQ + kt + sc8);
            __syncthreads();

            if (kt > qrow0 + 15) continue;     // fully masked for this wave

            // ---- QK^T (log2 units)
            f32x4 st[4];
            __builtin_amdgcn_s_setprio(1);
#pragma unroll
            for (int kk = 0; kk < 4; kk++) {
                const u16* kb = &Ks[(kk * 16 + am) * 72 + grp * 8];
                bf16x8 k0 = *(const bf16x8*)(kb);
                bf16x8 k1 = *(const bf16x8*)(kb + 32);
                f32x4 s = (f32x4){0.f, 0.f, 0.f, 0.f};
                s = __builtin_amdgcn_mfma_f32_16x16x32_bf16(qf[0], k0, s, 0, 0, 0);
                s = __builtin_amdgcn_mfma_f32_16x16x32_bf16(qf[1], k1, s, 0, 0, 0);
                st[kk] = s;
            }
            __builtin_amdgcn_s_setprio(0);
            if (kt + 63 > qrow0) {             // diagonal: apply causal mask
#pragma unroll
                for (int kk = 0; kk < 4; kk++) {
                    const int kg2 = kt + kk * 16 + am;
#pragma unroll
                    for (int r = 0; r < 4; r++) {
                        const int qg = qrow0 + grp * 4 + r;
                        if (kg2 > qg) st[kk][r] = -1e30f;
                    }
                }
            }
            // ---- static-max softmax: P = exp2(s), masked -> 0
#pragma unroll
            for (int kk = 0; kk < 4; kk++)
#pragma unroll
                for (int r = 0; r < 4; r++)
                    st[kk][r] = exp2f(st[kk][r]);

            // ---- P: C-layout -> per-wave LDS -> A-layout
            u16* pw = &Ps[wid][0];
#pragma unroll
            for (int kk = 0; kk < 4; kk++)
#pragma unroll
                for (int r = 0; r < 4; r++)
                    pw[(grp * 4 + r) * 72 + kk * 16 + am] = f2b_trunc(st[kk][r]);
            asm volatile("s_waitcnt lgkmcnt(0)" ::: "memory");

            // ---- PV + ones-column l accumulation
            __builtin_amdgcn_s_setprio(1);
#pragma unroll
            for (int hh = 0; hh < 2; hh++) {
                bf16x8 pf = *(const bf16x8*)(&pw[am * 72 + hh * 32 + grp * 8]);
                Ol = __builtin_amdgcn_mfma_f32_16x16x32_bf16(pf, ones, Ol, 0, 0, 0);
#pragma unroll
                for (int jt = 0; jt < 4; jt++) {
                    bf16x8 vf = *(const bf16x8*)(
                        &Vt[(jt * 16 + am) * 72 + hh * 32 + grp * 8]);
                    O[jt] = __builtin_amdgcn_mfma_f32_16x16x32_bf16(
                        pf, vf, O[jt], 0, 0, 0);
                }
            }
            __builtin_amdgcn_s_setprio(0);
        }

        // ---- epilogue for this q-tile
        u16* aorow = ao + (tok0 + qrow0) * 1024 + h * 64;
#pragma unroll
        for (int r = 0; r < 4; r++) {
            const int q = grp * 4 + r;
            const float invl = 1.f / Ol[r];
#pragma unroll
            for (int jt = 0; jt < 4; jt++)
                aorow[(size_t)q * 1024 + jt * 16 + am] = f2b(O[jt][r] * invl);
        }
    }
}

// ---------------------------------------------------------------------------
extern "C" void kernel_launch(void* const* d_in, const int* in_sizes, int n_in,
                              void* d_out, int out_size, void* d_ws, size_t ws_size,
                              hipStream_t stream)
{
    (void)in_sizes; (void)n_in; (void)out_size; (void)ws_size;
    const float* x     = (const float*)d_in[0];
    const float* wq    = (const float*)d_in[1];
    const float* wk    = (const float*)d_in[2];
    const float* wv    = (const float*)d_in[3];
    const float* wo    = (const float*)d_in[4];
    const float* ln1   = (const float*)d_in[5];
    const float* ln2   = (const float*)d_in[6];
    const float* wup   = (const float*)d_in[7];
    const float* wgate = (const float*)d_in[8];
    const float* wdown = (const float*)d_in[9];
    float* out = (float*)d_out;
    char* ws = (char*)d_ws;
    const size_t MB = 1024 * 1024;

    u16*   xn   = (u16*)(ws);
    u16*   ao   = (u16*)(ws);
    u16*   qkv  = (u16*)(ws + 16 * MB);
    u16*   hbuf = (u16*)(ws + 16 * MB);
    u16*   vtb  = (u16*)(ws + 64 * MB);
    float* x1   = (float*)(ws + 80 * MB);
    u16*   bwq  = (u16*)(ws + 112 * MB);
    u16*   bwk  = (u16*)(ws + 114 * MB);
    u16*   bwv  = (u16*)(ws + 116 * MB);
    u16*   bwo  = (u16*)(ws + 118 * MB);
    u16*   bwmu = (u16*)(ws + 120 * MB);             // gate/up interleaved, 16MB
    u16*   bwdn = (u16*)(ws + 136 * MB);
    float* cst  = (float*)(ws + 144 * MB);
    float* snt  = (float*)(ws + 144 * MB + 262144);

    cvt_all<<<16384, 256, 0, stream>>>(wq, wk, wv, wo, wup, wgate, wdown,
                                       bwq, bwk, bwv, bwo, bwmu, bwdn);

    rope_tab<<<SEQ, 32, 0, stream>>>(cst, snt);
    rmsnorm_k<<<NTOK, 256, 0, stream>>>(x, ln1, xn);
    gemm_bt<0><<<dim3(24, 64), 256, 0, stream>>>(xn, bwq, qkv, nullptr, NTOK, 3072, 1024, 3072, 0);
    rope_apply<<<NTOK, 256, 0, stream>>>(qkv, cst, snt);
    vtrans<<<dim3(64, 8), 256, 0, stream>>>(qkv, vtb);
    attn<<<dim3(64, 8), 512, 0, stream>>>(qkv, vtb, ao);
    gemm_bt<1><<<dim3(8, 64), 256, 0, stream>>>(ao, bwo, x1, x, NTOK, 1024, 1024, 1024, 0);
    rmsnorm_k<<<NTOK, 256, 0, stream>>>(x1, ln2, xn);
    gemm8_mlp<<<dim3(32, 32), 512, 0, stream>>>(xn, bwmu, hbuf);
    gemm_bt<1><<<dim3(8, 64), 256, 0, stream>>>(hbuf, bwdn, out, x1, NTOK, 1024, 4096, 1024, 0);
}

// Round 6
// 567.469 us; speedup vs baseline: 1.0345x; 1.0070x over previous
//
#include <hip/hip_runtime.h>
#include <stdint.h>

#define SEQ   2048
#define NTOK  8192   // 4 * 2048

typedef unsigned short u16;
typedef __bf16 bf16x8 __attribute__((ext_vector_type(8)));
typedef float  f32x4  __attribute__((ext_vector_type(4)));
typedef float  f32x16 __attribute__((ext_vector_type(16)));

__device__ __forceinline__ float b2f(u16 b) {
    union { unsigned u; float f; } v; v.u = ((unsigned)b) << 16; return v.f;
}
__device__ __forceinline__ u16 f2b(float f) {
    union { float f; unsigned u; } v; v.f = f;
    unsigned r = (v.u + 0x7fffu + ((v.u >> 16) & 1u)) >> 16;
    return (u16)r;
}
__device__ __forceinline__ u16 f2b_trunc(float f) {   // cheap, P >= 0
    union { float f; unsigned u; } v; v.f = f;
    return (u16)(v.u >> 16);
}

__device__ __forceinline__ void gl_lds16(const void* g, void* l) {
    __builtin_amdgcn_global_load_lds(
        (const __attribute__((address_space(1))) void*)g,
        (__attribute__((address_space(3))) void*)l,
        16, 0, 0);
}

// ---------------------------------------------------------------------------
// fp32 -> bf16 conversion, all 7 weight matrices in ONE dispatch.
// gate/up are interleaved into ONE combined matrix dmu[8192][1024]:
//   rows [32q..32q+16) = gate rows [16q..16q+16)
//   rows [32q+16..32q+32) = up rows [16q..16q+16)
// so the 8-phase MLP GEMM can pair gate/up register-locally (16-col frags).
// ---------------------------------------------------------------------------
__global__ __launch_bounds__(256)
void cvt_all(const float* __restrict__ wq, const float* __restrict__ wk,
             const float* __restrict__ wv, const float* __restrict__ wo,
             const float* __restrict__ wup, const float* __restrict__ wgt,
             const float* __restrict__ wdn,
             u16* __restrict__ dq, u16* __restrict__ dk, u16* __restrict__ dv,
             u16* __restrict__ dw, u16* __restrict__ dmu, u16* __restrict__ dd)
{
    const int bid = blockIdx.x;
    const float* s; u16* d; int osrc, odst;
    if (bid < 4096) {
        const int which = bid >> 10;
        osrc = odst = (bid & 1023) * 256 + threadIdx.x;
        s = which == 0 ? wq : which == 1 ? wk : which == 2 ? wv : wo;
        d = which == 0 ? dq : which == 1 ? dk : which == 2 ? dv : dw;
    } else {
        const int which = (bid - 4096) >> 12;     // 0=up 1=gate 2=down
        const int o = ((bid - 4096) & 4095) * 256 + threadIdx.x;
        osrc = o;
        if (which == 2) { s = wdn; d = dd; odst = o; }
        else {
            s = which == 0 ? wup : wgt;
            d = dmu;
            const int row = o >> 8;               // 256 float4 per 1024-col row
            const int rowp = ((row >> 4) << 5) + (row & 15) + (which == 0 ? 16 : 0);
            odst = rowp * 256 + (o & 255);
        }
    }
    float4 v = ((const float4*)s)[osrc];
    ushort4 ov;
    ov.x = f2b(v.x); ov.y = f2b(v.y); ov.z = f2b(v.z); ov.w = f2b(v.w);
    ((ushort4*)d)[odst] = ov;
}

// ---------------------------------------------------------------------------
// GEMM: C[M][N] = A[M][K] * B[N][K]^T   (bf16 in, fp32 accum)
// 128x128 tile, BK=64, XOR-swizzled LDS, mfma 32x32x16.
// EPI 0: bf16 C[idx] = acc
// EPI 1: f32  C[idx] = acc + E_f32[idx]          (fused residual, fp32 out)
// ---------------------------------------------------------------------------
template<int EPI>
__global__ __launch_bounds__(256)
void gemm_bt(const u16* __restrict__ A, const u16* __restrict__ B,
             void* __restrict__ C, const void* __restrict__ E,
             int M, int N, int K, int ldc, int coff)
{
    __shared__ __align__(16) u16 As[128 * 64];
    __shared__ __align__(16) u16 Bs[128 * 64];

    const int tid  = threadIdx.x;
    const int lane = tid & 63;
    const int wid  = tid >> 6;
    const int m0 = blockIdx.y * 128;
    const int n0 = blockIdx.x * 128;
    const int wm = (wid >> 1) * 64;
    const int wn = (wid & 1) * 64;
    const int l31 = lane & 31, kg = lane >> 5;

    f32x16 acc[2][2];
#pragma unroll
    for (int i = 0; i < 2; i++)
#pragma unroll
        for (int j = 0; j < 2; j++)
#pragma unroll
            for (int r = 0; r < 16; r++) acc[i][j][r] = 0.f;

    const u16* Ag[4]; const u16* Bg[4]; u16* Al[4]; u16* Bl[4];
#pragma unroll
    for (int j = 0; j < 4; j++) {
        const int q = j * 256 + tid;
        const int r = q >> 3, s = q & 7, c = s ^ (r & 7);
        Ag[j] = A + (size_t)(m0 + r) * K + c * 8;
        Bg[j] = B + (size_t)(n0 + r) * K + c * 8;
        Al[j] = As + q * 8;
        Bl[j] = Bs + q * 8;
    }

    int arow[2], brow[2];
#pragma unroll
    for (int i = 0; i < 2; i++) { arow[i] = wm + i * 32 + l31; }
#pragma unroll
    for (int j = 0; j < 2; j++) { brow[j] = wn + j * 32 + l31; }

    for (int kt = 0; kt < K; kt += 64) {
        __syncthreads();
#pragma unroll
        for (int j = 0; j < 4; j++) {
            gl_lds16(Ag[j] + kt, Al[j]);
            gl_lds16(Bg[j] + kt, Bl[j]);
        }
        __syncthreads();

#pragma unroll
        for (int s = 0; s < 4; s++) {
            const int ch = s * 2 + kg;
            bf16x8 af[2], bf[2];
#pragma unroll
            for (int i = 0; i < 2; i++)
                af[i] = *(const bf16x8*)(
                    &As[arow[i] * 64 + ((ch ^ (arow[i] & 7)) * 8)]);
#pragma unroll
            for (int j = 0; j < 2; j++)
                bf[j] = *(const bf16x8*)(
                    &Bs[brow[j] * 64 + ((ch ^ (brow[j] & 7)) * 8)]);
#pragma unroll
            for (int i = 0; i < 2; i++)
#pragma unroll
                for (int j = 0; j < 2; j++)
                    acc[i][j] = __builtin_amdgcn_mfma_f32_32x32x16_bf16(
                        af[i], bf[j], acc[i][j], 0, 0, 0);
        }
    }

#pragma unroll
    for (int i = 0; i < 2; i++) {
#pragma unroll
        for (int r = 0; r < 16; r++) {
            const int row = m0 + wm + i * 32 + (r & 3) + 8 * (r >> 2) + 4 * kg;
#pragma unroll
            for (int j = 0; j < 2; j++) {
                const int col = n0 + wn + j * 32 + l31;
                const size_t idx = (size_t)row * ldc + coff + col;
                const float v = acc[i][j][r];
                if (EPI == 0) {
                    ((u16*)C)[idx] = f2b(v);
                } else {
                    ((float*)C)[idx] = v + ((const float*)E)[idx];
                }
            }
        }
    }
}

// ---------------------------------------------------------------------------
// Shared 8-phase scheduling macros (validated in gemm8_mlp, R0/R1 passes).
// ---------------------------------------------------------------------------
#define MIDBAR \
    __builtin_amdgcn_s_barrier(); \
    asm volatile("s_waitcnt lgkmcnt(0)" ::: "memory"); \
    __builtin_amdgcn_sched_barrier(0);

#define PBAR \
    __builtin_amdgcn_s_barrier(); \
    asm volatile("" ::: "memory"); \
    __builtin_amdgcn_sched_barrier(0);

#define VMBARN(n) \
    asm volatile("s_waitcnt vmcnt(" #n ")" ::: "memory"); \
    __builtin_amdgcn_s_barrier(); \
    asm volatile("" ::: "memory"); \
    __builtin_amdgcn_sched_barrier(0);

// ---------------------------------------------------------------------------
// 8-phase 256x256 MLP GEMM (gate+up combined, N=8192 interleaved), BK=64,
// 512 thr = 8 waves (2M x 4N), per-wave 128x64 out, mfma 16x16x32.
// LDS 128 KiB: As/Bs = 2 dbuf x 2 half(128 rows) x [128][64] XOR-swizzled.
// Counted vmcnt (4), never 0 in steady state.  Epilogue: silu(up)*gate.
// ---------------------------------------------------------------------------
#define LDA(bufi, mh) { \
    const u16* _ab = Ab##bufi + (mh) * 4096; \
    _Pragma("unroll") \
    for (int _m = 0; _m < 4; ++_m) { \
        Aq[_m][0] = *(const bf16x8*)(_ab + _m * 1024 + axor0); \
        Aq[_m][1] = *(const bf16x8*)(_ab + _m * 1024 + axor1); \
    } }

#define LDB(bufi, nh) { \
    const u16* _bb = Bb##bufi + (nh) * 2048; \
    _Pragma("unroll") \
    for (int _n = 0; _n < 2; ++_n) { \
        Bq[nh][_n][0] = *(const bf16x8*)(_bb + _n * 1024 + axor0); \
        Bq[nh][_n][1] = *(const bf16x8*)(_bb + _n * 1024 + axor1); \
    } }

#define MM(mh, nh) \
    __builtin_amdgcn_s_setprio(1); \
    { _Pragma("unroll") \
      for (int _m = 0; _m < 4; ++_m) { \
        _Pragma("unroll") \
        for (int _n = 0; _n < 2; ++_n) { \
            acc[(mh)*4+_m][(nh)*2+_n] = __builtin_amdgcn_mfma_f32_16x16x32_bf16( \
                Aq[_m][0], Bq[nh][_n][0], acc[(mh)*4+_m][(nh)*2+_n], 0, 0, 0); \
            acc[(mh)*4+_m][(nh)*2+_n] = __builtin_amdgcn_mfma_f32_16x16x32_bf16( \
                Aq[_m][1], Bq[nh][_n][1], acc[(mh)*4+_m][(nh)*2+_n], 0, 0, 0); \
        } } } \
    __builtin_amdgcn_s_setprio(0);

#define STAGE_A(tile, half) { \
    const u16* _s = pA0 + (size_t)(half) * 131072 + (size_t)(tile) * 64; \
    u16* _d = lA0 + ((tile) & 1) * 16384 + (half) * 8192; \
    gl_lds16(_s, _d); \
    gl_lds16(_s + 65536, _d + 4096); }

#define STAGE_B(tile, half) { \
    const u16* _s = pB0 + (size_t)(half) * 131072 + (size_t)(tile) * 64; \
    u16* _d = lB0 + ((tile) & 1) * 16384 + (half) * 8192; \
    gl_lds16(_s, _d); \
    gl_lds16(_s + 65536, _d + 4096); }

__global__ __launch_bounds__(512, 2)
void gemm8_mlp(const u16* __restrict__ A, const u16* __restrict__ Bc,
               u16* __restrict__ H)
{
    __shared__ __align__(16) u16 As[32768];   // 2 buf x 2 half x 128 x 64
    __shared__ __align__(16) u16 Bs[32768];

    const int tid = threadIdx.x, lane = tid & 63, wid = tid >> 6;
    const int wr = wid >> 2, wc = wid & 3;
    const int r15 = lane & 15, ks = lane >> 4;
    const int m0 = blockIdx.y * 256, n0 = blockIdx.x * 256;

    // per-lane swizzled frag offsets: slot = (kf*4+ks) ^ (row&7)
    const int axor0 = ((ks) ^ (r15 & 7)) * 8;
    const int axor1 = ((4 + ks) ^ (r15 & 7)) * 8;
    const u16* Ab0 = As + wr * 8192 + r15 * 64;
    const u16* Ab1 = As + 16384 + wr * 8192 + r15 * 64;
    const u16* Bb0 = Bs + (wc >> 1) * 8192 + (wc & 1) * 4096 + r15 * 64;
    const u16* Bb1 = Bs + 16384 + (wc >> 1) * 8192 + (wc & 1) * 4096 + r15 * 64;

    // staging: thread t covers chunk q=t (rows 0..63) and q=512+t (rows 64..127)
    const int r0 = tid >> 3, c0 = (tid & 7) ^ (r0 & 7);
    const u16* pA0 = A  + (size_t)(m0 + r0) * 1024 + c0 * 8;
    const u16* pB0 = Bc + (size_t)(n0 + r0) * 1024 + c0 * 8;
    u16* lA0 = As + tid * 8;
    u16* lB0 = Bs + tid * 8;

    f32x4 acc[8][4];
#pragma unroll
    for (int m = 0; m < 8; ++m)
#pragma unroll
        for (int n = 0; n < 4; ++n)
            acc[m][n] = (f32x4){0.f, 0.f, 0.f, 0.f};

    bf16x8 Aq[4][2], Bq[2][2][2];

    // ---- prologue: tile0 (all 4 halves) + tile1 (B0,B1); keep tile1's 2 in flight
    STAGE_A(0, 0); STAGE_A(0, 1);
    STAGE_B(0, 0); STAGE_B(0, 1);
    STAGE_B(1, 0); STAGE_B(1, 1);
    asm volatile("s_waitcnt vmcnt(4)" ::: "memory");
    __builtin_amdgcn_s_barrier();
    asm volatile("" ::: "memory");
    __builtin_amdgcn_sched_barrier(0);

    for (int i = 0; i < 8; ++i) {
        const int t1 = 2 * i + 1;
        const int t2 = 2 * i + 2;
        const int t3 = 2 * i + 3;
        const bool st = (i < 7);      // t2<16 and t3<16

        // ---- phase 1: quad(0,0) of tile 2i (buf0)
        LDA(0, 0); LDB(0, 0);
        STAGE_A(t1, 0);
        MIDBAR; MM(0, 0); PBAR;
        // ---- phase 2: quad(0,1)
        LDB(0, 1);
        STAGE_A(t1, 1);
        MIDBAR; MM(0, 1); PBAR;
        // ---- phase 3: quad(1,1)
        LDA(0, 1);
        if (st) STAGE_B(t2, 0);
        MIDBAR; MM(1, 1); PBAR;
        // ---- phase 4: quad(1,0); retire tile 2i+1 (needed p5-8)
        if (st) STAGE_B(t2, 1);
        MIDBAR; MM(1, 0);
        if (i == 7) { VMBARN(0); } else { VMBARN(4); }

        // ---- phase 5: quad(0,0) of tile 2i+1 (buf1)
        LDA(1, 0); LDB(1, 0);
        if (st) STAGE_A(t2, 0);
        MIDBAR; MM(0, 0); PBAR;
        // ---- phase 6: quad(0,1)
        LDB(1, 1);
        if (st) STAGE_A(t2, 1);
        MIDBAR; MM(0, 1); PBAR;
        // ---- phase 7: quad(1,1)
        LDA(1, 1);
        if (st) STAGE_B(t3, 0);
        MIDBAR; MM(1, 1); PBAR;
        // ---- phase 8: quad(1,0); retire tile 2i+2 (needed next p1-4)
        if (st) STAGE_B(t3, 1);
        MIDBAR; MM(1, 0);
        VMBARN(4);
    }

    // ---- epilogue: silu(up)*gate, register-local pairs (n=2p gate, 2p+1 up)
    const int orow0 = m0 + wr * 128;
    const int ocol0 = (n0 >> 1) + wc * 32;
#pragma unroll
    for (int m = 0; m < 8; ++m) {
#pragma unroll
        for (int p = 0; p < 2; ++p) {
#pragma unroll
            for (int r = 0; r < 4; ++r) {
                const int row = orow0 + m * 16 + ks * 4 + r;
                const int col = ocol0 + p * 16 + r15;
                const float g = acc[m][2 * p][r];
                const float u = acc[m][2 * p + 1][r];
                H[(size_t)row * 4096 + col] = f2b(u / (1.f + __expf(-u)) * g);
            }
        }
    }
}

// ---------------------------------------------------------------------------
// RMSNorm: fp32 in, fp32 weight, bf16 out. One block/token, 256 thr x 4 elems
// ---------------------------------------------------------------------------
__global__ __launch_bounds__(256)
void rmsnorm_k(const float* __restrict__ xin, const float* __restrict__ w,
               u16* __restrict__ o)
{
    const int t = blockIdx.x;
    const int tid = threadIdx.x;
    float4 xv = ((const float4*)xin)[(size_t)t * 256 + tid];
    float ss = xv.x * xv.x + xv.y * xv.y + xv.z * xv.z + xv.w * xv.w;
#pragma unroll
    for (int off = 32; off > 0; off >>= 1) ss += __shfl_down(ss, off);
    __shared__ float red[4];
    const int lane = tid & 63, wv_ = tid >> 6;
    if (lane == 0) red[wv_] = ss;
    __syncthreads();
    const float tot = red[0] + red[1] + red[2] + red[3];
    const float inv = rsqrtf(tot * (1.f / 1024.f) + 1e-5f);
    float4 ww = ((const float4*)w)[tid];
    ushort4 ov;
    ov.x = f2b(xv.x * inv * ww.x);
    ov.y = f2b(xv.y * inv * ww.y);
    ov.z = f2b(xv.z * inv * ww.z);
    ov.w = f2b(xv.w * inv * ww.w);
    ((ushort4*)o)[(size_t)t * 256 + tid] = ov;
}

// ---------------------------------------------------------------------------
// RoPE tables + apply. Q scaled by 0.125*log2(e) so attn can use exp2.
// ---------------------------------------------------------------------------
#define QSCALE 0.18033688011112042f   // (1/sqrt(64)) * log2(e)

__global__ void rope_tab(float* __restrict__ cs, float* __restrict__ sn)
{
    const int s = blockIdx.x;
    const int i = threadIdx.x;
    const double inv = exp(-((double)(2 * i) / 64.0) * log(10000.0));
    const double ang = (double)s * inv;
    cs[s * 32 + i] = (float)cos(ang);
    sn[s * 32 + i] = (float)sin(ang);
}

__global__ __launch_bounds__(256)
void rope_apply(u16* __restrict__ qkv, const float* __restrict__ cs,
                const float* __restrict__ sn)
{
    const int t = blockIdx.x;
    const int s = t & (SEQ - 1);
    u16* row = qkv + (size_t)t * 3072;
    __shared__ float c_s[32], s_s[32];
    if (threadIdx.x < 32) {
        c_s[threadIdx.x] = cs[s * 32 + threadIdx.x];
        s_s[threadIdx.x] = sn[s * 32 + threadIdx.x];
    }
    __syncthreads();
#pragma unroll
    for (int rr = 0; rr < 2; rr++) {
        const int item = rr * 256 + threadIdx.x;
        const int hh = item >> 5, i = item & 31;
        const int f = hh * 64 + 2 * i;
        const float c = c_s[i], sv = s_s[i];
        float xe = b2f(row[f]), xo = b2f(row[f + 1]);
        row[f]     = f2b((xe * c - xo * sv) * QSCALE);   // Q: fold scale+log2e
        row[f + 1] = f2b((xo * c + xe * sv) * QSCALE);
        xe = b2f(row[1024 + f]); xo = b2f(row[1024 + f + 1]);
        row[1024 + f]     = f2b(xe * c - xo * sv);       // K: unscaled
        row[1024 + f + 1] = f2b(xo * c + xe * sv);
    }
}

// ---------------------------------------------------------------------------
// V pre-transpose: vt[bh][d][s] from qkv v-columns. LDS-tiled, one-shot.
// ---------------------------------------------------------------------------
__global__ __launch_bounds__(256)
void vtrans(const u16* __restrict__ qkv, u16* __restrict__ vt)
{
    __shared__ u16 Ld[64 * 264];
    const int bh = blockIdx.x, st = blockIdx.y;
    const int b = bh >> 4, h = bh & 15;
    const int tid = threadIdx.x;
    const u16* src = qkv + ((size_t)(b * SEQ + st * 256 + tid)) * 3072 + 2048 + h * 64;
    uint4 v[8];
#pragma unroll
    for (int c = 0; c < 8; c++) v[c] = *(const uint4*)(src + c * 8);
#pragma unroll
    for (int c = 0; c < 8; c++) {
        const u16* pv = (const u16*)&v[c];
#pragma unroll
        for (int j = 0; j < 8; j++)
            Ld[(c * 8 + j) * 264 + tid] = pv[j];
    }
    __syncthreads();
    u16* dst = vt + (size_t)bh * (64 * SEQ) + st * 256;
#pragma unroll
    for (int cc = 0; cc < 8; cc++) {
        const int c = cc * 256 + tid;
        const int d = c >> 5, t8 = (c & 31) * 8;
        *(uint4*)(dst + (size_t)d * SEQ + t8) = *(const uint4*)(&Ld[d * 264 + t8]);
    }
}

// ---------------------------------------------------------------------------
// Flash attention (causal), static-max softmax: P = exp2(s) directly (Q
// pre-scaled by 0.125*log2e). l via ones-column MFMA. Block = 512 thr,
// 2 q-tiles of 128 rows (qy, 15-qy). K [64][72], V^T [64][72] per kv-tile.
// R6: SWAPPED QK^T — compute mfma(K, Q) = S^T so each lane holds 4
// consecutive k (k = kk*16 + grp*4 + r, q = am). P C->A bounce becomes
// 4x ds_write_b64 (packed ushort4) instead of 16x ds_write_b16.
// Staging kept as R1 (regular loads between barriers — compiler prefetches;
// manual gl_lds measured +21 µs in R4; setprio measured +5 µs in R5).
// ---------------------------------------------------------------------------
__global__ __launch_bounds__(512)
void attn(const u16* __restrict__ qkv, const u16* __restrict__ vt,
          u16* __restrict__ ao)
{
    __shared__ __align__(16) u16 Ks[64 * 72];
    __shared__ __align__(16) u16 Vt[64 * 72];
    __shared__ __align__(16) u16 Ps[8][16 * 72];

    const int bh = blockIdx.x;
    const int qy = blockIdx.y;                 // 0..7
    const int b = bh >> 4, h = bh & 15;
    const int tid = threadIdx.x, lane = tid & 63, wid = tid >> 6;
    const int am = lane & 15, grp = lane >> 4;
    const size_t tok0 = (size_t)b * SEQ;
    const u16* qbase = qkv + tok0 * 3072 + h * 64;
    const u16* kbase = qbase + 1024;
    const u16* vtg = vt + (size_t)bh * (64 * SEQ);

    union { uint4 u; bf16x8 b; } onesu;
    onesu.u = (uint4){0x3f803f80u, 0x3f803f80u, 0x3f803f80u, 0x3f803f80u};
    const bf16x8 ones = onesu.b;

    const int srow = tid >> 3, sc8 = (tid & 7) * 8;   // staging: 1 chunk each

#pragma unroll
    for (int tile = 0; tile < 2; tile++) {
        const int yt = tile == 0 ? qy : 15 - qy;
        const int qrow0 = yt * 128 + wid * 16;

        bf16x8 qf[2];
        {
            const u16* qp = qbase + (size_t)(qrow0 + am) * 3072 + grp * 8;
            qf[0] = *(const bf16x8*)(qp);
            qf[1] = *(const bf16x8*)(qp + 32);
        }

        f32x4 O[4], Ol;
#pragma unroll
        for (int j = 0; j < 4; j++) O[j] = (f32x4){0.f, 0.f, 0.f, 0.f};
        Ol = (f32x4){0.f, 0.f, 0.f, 0.f};

        const int ktend = yt * 128 + 64;       // last kv-tile start
        for (int kt = 0; kt <= ktend; kt += 64) {
            __syncthreads();
            *(uint4*)(&Ks[srow * 72 + sc8]) =
                *(const uint4*)(kbase + (size_t)(kt + srow) * 3072 + sc8);
            *(uint4*)(&Vt[srow * 72 + sc8]) =
                *(const uint4*)(vtg + (size_t)srow * SEQ + kt + sc8);
            __syncthreads();

            if (kt > qrow0 + 15) continue;     // fully masked for this wave

            // ---- QK^T swapped: st = S^T block. Lane holds rows
            // k = kk*16 + grp*4 + r, col q = qrow0 + am.
            f32x4 st[4];
#pragma unroll
            for (int kk = 0; kk < 4; kk++) {
                const u16* kb = &Ks[(kk * 16 + am) * 72 + grp * 8];
                bf16x8 k0 = *(const bf16x8*)(kb);
                bf16x8 k1 = *(const bf16x8*)(kb + 32);
                f32x4 s = (f32x4){0.f, 0.f, 0.f, 0.f};
                s = __builtin_amdgcn_mfma_f32_16x16x32_bf16(k0, qf[0], s, 0, 0, 0);
                s = __builtin_amdgcn_mfma_f32_16x16x32_bf16(k1, qf[1], s, 0, 0, 0);
                st[kk] = s;
            }
            if (kt + 63 > qrow0) {             // diagonal: apply causal mask
                const int qg = qrow0 + am;
#pragma unroll
                for (int kk = 0; kk < 4; kk++) {
                    const int kb2 = kt + kk * 16 + grp * 4;
#pragma unroll
                    for (int r = 0; r < 4; r++) {
                        if (kb2 + r > qg) st[kk][r] = -1e30f;
                    }
                }
            }
            // ---- static-max softmax: P = exp2(s), masked -> 0
#pragma unroll
            for (int kk = 0; kk < 4; kk++)
#pragma unroll
                for (int r = 0; r < 4; r++)
                    st[kk][r] = exp2f(st[kk][r]);

            // ---- P: S^T layout -> per-wave LDS [q=am][k], packed b64 writes
            u16* pw = &Ps[wid][0];
#pragma unroll
            for (int kk = 0; kk < 4; kk++) {
                ushort4 pk;
                pk.x = f2b_trunc(st[kk][0]);
                pk.y = f2b_trunc(st[kk][1]);
                pk.z = f2b_trunc(st[kk][2]);
                pk.w = f2b_trunc(st[kk][3]);
                *(ushort4*)(&pw[am * 72 + kk * 16 + grp * 4]) = pk;
            }
            asm volatile("s_waitcnt lgkmcnt(0)" ::: "memory");

            // ---- PV + ones-column l accumulation
#pragma unroll
            for (int hh = 0; hh < 2; hh++) {
                bf16x8 pf = *(const bf16x8*)(&pw[am * 72 + hh * 32 + grp * 8]);
                Ol = __builtin_amdgcn_mfma_f32_16x16x32_bf16(pf, ones, Ol, 0, 0, 0);
#pragma unroll
                for (int jt = 0; jt < 4; jt++) {
                    bf16x8 vf = *(const bf16x8*)(
                        &Vt[(jt * 16 + am) * 72 + hh * 32 + grp * 8]);
                    O[jt] = __builtin_amdgcn_mfma_f32_16x16x32_bf16(
                        pf, vf, O[jt], 0, 0, 0);
                }
            }
        }

        // ---- epilogue for this q-tile
        u16* aorow = ao + (tok0 + qrow0) * 1024 + h * 64;
#pragma unroll
        for (int r = 0; r < 4; r++) {
            const int q = grp * 4 + r;
            const float invl = 1.f / Ol[r];
#pragma unroll
            for (int jt = 0; jt < 4; jt++)
                aorow[(size_t)q * 1024 + jt * 16 + am] = f2b(O[jt][r] * invl);
        }
    }
}

// ---------------------------------------------------------------------------
extern "C" void kernel_launch(void* const* d_in, const int* in_sizes, int n_in,
                              void* d_out, int out_size, void* d_ws, size_t ws_size,
                              hipStream_t stream)
{
    (void)in_sizes; (void)n_in; (void)out_size; (void)ws_size;
    const float* x     = (const float*)d_in[0];
    const float* wq    = (const float*)d_in[1];
    const float* wk    = (const float*)d_in[2];
    const float* wv    = (const float*)d_in[3];
    const float* wo    = (const float*)d_in[4];
    const float* ln1   = (const float*)d_in[5];
    const float* ln2   = (const float*)d_in[6];
    const float* wup   = (const float*)d_in[7];
    const float* wgate = (const float*)d_in[8];
    const float* wdown = (const float*)d_in[9];
    float* out = (float*)d_out;
    char* ws = (char*)d_ws;
    const size_t MB = 1024 * 1024;

    u16*   xn   = (u16*)(ws);
    u16*   ao   = (u16*)(ws);
    u16*   qkv  = (u16*)(ws + 16 * MB);
    u16*   hbuf = (u16*)(ws + 16 * MB);
    u16*   vtb  = (u16*)(ws + 64 * MB);
    float* x1   = (float*)(ws + 80 * MB);
    u16*   bwq  = (u16*)(ws + 112 * MB);
    u16*   bwk  = (u16*)(ws + 114 * MB);
    u16*   bwv  = (u16*)(ws + 116 * MB);
    u16*   bwo  = (u16*)(ws + 118 * MB);
    u16*   bwmu = (u16*)(ws + 120 * MB);             // gate/up interleaved, 16MB
    u16*   bwdn = (u16*)(ws + 136 * MB);
    float* cst  = (float*)(ws + 144 * MB);
    float* snt  = (float*)(ws + 144 * MB + 262144);

    cvt_all<<<16384, 256, 0, stream>>>(wq, wk, wv, wo, wup, wgate, wdown,
                                       bwq, bwk, bwv, bwo, bwmu, bwdn);

    rope_tab<<<SEQ, 32, 0, stream>>>(cst, snt);
    rmsnorm_k<<<NTOK, 256, 0, stream>>>(x, ln1, xn);
    gemm_bt<0><<<dim3(24, 64), 256, 0, stream>>>(xn, bwq, qkv, nullptr, NTOK, 3072, 1024, 3072, 0);
    rope_apply<<<NTOK, 256, 0, stream>>>(qkv, cst, snt);
    vtrans<<<dim3(64, 8), 256, 0, stream>>>(qkv, vtb);
    attn<<<dim3(64, 8), 512, 0, stream>>>(qkv, vtb, ao);
    gemm_bt<1><<<dim3(8, 64), 256, 0, stream>>>(ao, bwo, x1, x, NTOK, 1024, 1024, 1024, 0);
    rmsnorm_k<<<NTOK, 256, 0, stream>>>(x1, ln2, xn);
    gemm8_mlp<<<dim3(32, 32), 512, 0, stream>>>(xn, bwmu, hbuf);
    gemm_bt<1><<<dim3(8, 64), 256, 0, stream>>>(hbuf, bwdn, out, x1, NTOK, 1024, 4096, 1024, 0);
}

// Round 7
// 564.459 us; speedup vs baseline: 1.0401x; 1.0053x over previous
//
#include <hip/hip_runtime.h>
#include <stdint.h>

#define SEQ   2048
#define NTOK  8192   // 4 * 2048

typedef unsigned short u16;
typedef __bf16 bf16x8 __attribute__((ext_vector_type(8)));
typedef float  f32x4  __attribute__((ext_vector_type(4)));
typedef float  f32x16 __attribute__((ext_vector_type(16)));

__device__ __forceinline__ float b2f(u16 b) {
    union { unsigned u; float f; } v; v.u = ((unsigned)b) << 16; return v.f;
}
__device__ __forceinline__ u16 f2b(float f) {
    union { float f; unsigned u; } v; v.f = f;
    unsigned r = (v.u + 0x7fffu + ((v.u >> 16) & 1u)) >> 16;
    return (u16)r;
}
__device__ __forceinline__ u16 f2b_trunc(float f) {   // cheap, P >= 0
    union { float f; unsigned u; } v; v.f = f;
    return (u16)(v.u >> 16);
}

__device__ __forceinline__ void gl_lds16(const void* g, void* l) {
    __builtin_amdgcn_global_load_lds(
        (const __attribute__((address_space(1))) void*)g,
        (__attribute__((address_space(3))) void*)l,
        16, 0, 0);
}

// ---------------------------------------------------------------------------
// fp32 -> bf16 conversion, all 7 weight matrices in ONE dispatch.
// gate/up are interleaved into ONE combined matrix dmu[8192][1024]:
//   rows [32q..32q+16) = gate rows [16q..16q+16)
//   rows [32q+16..32q+32) = up rows [16q..16q+16)
// so the 8-phase MLP GEMM can pair gate/up register-locally (16-col frags).
// ---------------------------------------------------------------------------
__global__ __launch_bounds__(256)
void cvt_all(const float* __restrict__ wq, const float* __restrict__ wk,
             const float* __restrict__ wv, const float* __restrict__ wo,
             const float* __restrict__ wup, const float* __restrict__ wgt,
             const float* __restrict__ wdn,
             u16* __restrict__ dq, u16* __restrict__ dk, u16* __restrict__ dv,
             u16* __restrict__ dw, u16* __restrict__ dmu, u16* __restrict__ dd)
{
    const int bid = blockIdx.x;
    const float* s; u16* d; int osrc, odst;
    if (bid < 4096) {
        const int which = bid >> 10;
        osrc = odst = (bid & 1023) * 256 + threadIdx.x;
        s = which == 0 ? wq : which == 1 ? wk : which == 2 ? wv : wo;
        d = which == 0 ? dq : which == 1 ? dk : which == 2 ? dv : dw;
    } else {
        const int which = (bid - 4096) >> 12;     // 0=up 1=gate 2=down
        const int o = ((bid - 4096) & 4095) * 256 + threadIdx.x;
        osrc = o;
        if (which == 2) { s = wdn; d = dd; odst = o; }
        else {
            s = which == 0 ? wup : wgt;
            d = dmu;
            const int row = o >> 8;               // 256 float4 per 1024-col row
            const int rowp = ((row >> 4) << 5) + (row & 15) + (which == 0 ? 16 : 0);
            odst = rowp * 256 + (o & 255);
        }
    }
    float4 v = ((const float4*)s)[osrc];
    ushort4 ov;
    ov.x = f2b(v.x); ov.y = f2b(v.y); ov.z = f2b(v.z); ov.w = f2b(v.w);
    ((ushort4*)d)[odst] = ov;
}

// ---------------------------------------------------------------------------
// GEMM: C[M][N] = A[M][K] * B[N][K]^T   (bf16 in, fp32 accum)
// 128x128 tile, BK=64, XOR-swizzled LDS, mfma 32x32x16.
// EPI 0: bf16 C[idx] = acc
// EPI 1: f32  C[idx] = acc + E_f32[idx]          (fused residual, fp32 out)
// ---------------------------------------------------------------------------
template<int EPI>
__global__ __launch_bounds__(256)
void gemm_bt(const u16* __restrict__ A, const u16* __restrict__ B,
             void* __restrict__ C, const void* __restrict__ E,
             int M, int N, int K, int ldc, int coff)
{
    __shared__ __align__(16) u16 As[128 * 64];
    __shared__ __align__(16) u16 Bs[128 * 64];

    const int tid  = threadIdx.x;
    const int lane = tid & 63;
    const int wid  = tid >> 6;
    const int m0 = blockIdx.y * 128;
    const int n0 = blockIdx.x * 128;
    const int wm = (wid >> 1) * 64;
    const int wn = (wid & 1) * 64;
    const int l31 = lane & 31, kg = lane >> 5;

    f32x16 acc[2][2];
#pragma unroll
    for (int i = 0; i < 2; i++)
#pragma unroll
        for (int j = 0; j < 2; j++)
#pragma unroll
            for (int r = 0; r < 16; r++) acc[i][j][r] = 0.f;

    const u16* Ag[4]; const u16* Bg[4]; u16* Al[4]; u16* Bl[4];
#pragma unroll
    for (int j = 0; j < 4; j++) {
        const int q = j * 256 + tid;
        const int r = q >> 3, s = q & 7, c = s ^ (r & 7);
        Ag[j] = A + (size_t)(m0 + r) * K + c * 8;
        Bg[j] = B + (size_t)(n0 + r) * K + c * 8;
        Al[j] = As + q * 8;
        Bl[j] = Bs + q * 8;
    }

    int arow[2], brow[2];
#pragma unroll
    for (int i = 0; i < 2; i++) { arow[i] = wm + i * 32 + l31; }
#pragma unroll
    for (int j = 0; j < 2; j++) { brow[j] = wn + j * 32 + l31; }

    for (int kt = 0; kt < K; kt += 64) {
        __syncthreads();
#pragma unroll
        for (int j = 0; j < 4; j++) {
            gl_lds16(Ag[j] + kt, Al[j]);
            gl_lds16(Bg[j] + kt, Bl[j]);
        }
        __syncthreads();

#pragma unroll
        for (int s = 0; s < 4; s++) {
            const int ch = s * 2 + kg;
            bf16x8 af[2], bf[2];
#pragma unroll
            for (int i = 0; i < 2; i++)
                af[i] = *(const bf16x8*)(
                    &As[arow[i] * 64 + ((ch ^ (arow[i] & 7)) * 8)]);
#pragma unroll
            for (int j = 0; j < 2; j++)
                bf[j] = *(const bf16x8*)(
                    &Bs[brow[j] * 64 + ((ch ^ (brow[j] & 7)) * 8)]);
#pragma unroll
            for (int i = 0; i < 2; i++)
#pragma unroll
                for (int j = 0; j < 2; j++)
                    acc[i][j] = __builtin_amdgcn_mfma_f32_32x32x16_bf16(
                        af[i], bf[j], acc[i][j], 0, 0, 0);
        }
    }

#pragma unroll
    for (int i = 0; i < 2; i++) {
#pragma unroll
        for (int r = 0; r < 16; r++) {
            const int row = m0 + wm + i * 32 + (r & 3) + 8 * (r >> 2) + 4 * kg;
#pragma unroll
            for (int j = 0; j < 2; j++) {
                const int col = n0 + wn + j * 32 + l31;
                const size_t idx = (size_t)row * ldc + coff + col;
                const float v = acc[i][j][r];
                if (EPI == 0) {
                    ((u16*)C)[idx] = f2b(v);
                } else {
                    ((float*)C)[idx] = v + ((const float*)E)[idx];
                }
            }
        }
    }
}

// ---------------------------------------------------------------------------
// Shared 8-phase scheduling macros (validated in gemm8_mlp, R0/R1 passes).
// ---------------------------------------------------------------------------
#define MIDBAR \
    __builtin_amdgcn_s_barrier(); \
    asm volatile("s_waitcnt lgkmcnt(0)" ::: "memory"); \
    __builtin_amdgcn_sched_barrier(0);

#define PBAR \
    __builtin_amdgcn_s_barrier(); \
    asm volatile("" ::: "memory"); \
    __builtin_amdgcn_sched_barrier(0);

#define VMBARN(n) \
    asm volatile("s_waitcnt vmcnt(" #n ")" ::: "memory"); \
    __builtin_amdgcn_s_barrier(); \
    asm volatile("" ::: "memory"); \
    __builtin_amdgcn_sched_barrier(0);

// ---------------------------------------------------------------------------
// 8-phase 256x256 MLP GEMM (gate+up combined, N=8192 interleaved), BK=64,
// 512 thr = 8 waves (2M x 4N), per-wave 128x64 out, mfma 16x16x32.
// LDS 128 KiB: As/Bs = 2 dbuf x 2 half(128 rows) x [128][64] XOR-swizzled.
// Counted vmcnt (4), never 0 in steady state.  Epilogue: silu(up)*gate.
// ---------------------------------------------------------------------------
#define LDA(bufi, mh) { \
    const u16* _ab = Ab##bufi + (mh) * 4096; \
    _Pragma("unroll") \
    for (int _m = 0; _m < 4; ++_m) { \
        Aq[_m][0] = *(const bf16x8*)(_ab + _m * 1024 + axor0); \
        Aq[_m][1] = *(const bf16x8*)(_ab + _m * 1024 + axor1); \
    } }

#define LDB(bufi, nh) { \
    const u16* _bb = Bb##bufi + (nh) * 2048; \
    _Pragma("unroll") \
    for (int _n = 0; _n < 2; ++_n) { \
        Bq[nh][_n][0] = *(const bf16x8*)(_bb + _n * 1024 + axor0); \
        Bq[nh][_n][1] = *(const bf16x8*)(_bb + _n * 1024 + axor1); \
    } }

#define MM(mh, nh) \
    __builtin_amdgcn_s_setprio(1); \
    { _Pragma("unroll") \
      for (int _m = 0; _m < 4; ++_m) { \
        _Pragma("unroll") \
        for (int _n = 0; _n < 2; ++_n) { \
            acc[(mh)*4+_m][(nh)*2+_n] = __builtin_amdgcn_mfma_f32_16x16x32_bf16( \
                Aq[_m][0], Bq[nh][_n][0], acc[(mh)*4+_m][(nh)*2+_n], 0, 0, 0); \
            acc[(mh)*4+_m][(nh)*2+_n] = __builtin_amdgcn_mfma_f32_16x16x32_bf16( \
                Aq[_m][1], Bq[nh][_n][1], acc[(mh)*4+_m][(nh)*2+_n], 0, 0, 0); \
        } } } \
    __builtin_amdgcn_s_setprio(0);

#define STAGE_A(tile, half) { \
    const u16* _s = pA0 + (size_t)(half) * 131072 + (size_t)(tile) * 64; \
    u16* _d = lA0 + ((tile) & 1) * 16384 + (half) * 8192; \
    gl_lds16(_s, _d); \
    gl_lds16(_s + 65536, _d + 4096); }

#define STAGE_B(tile, half) { \
    const u16* _s = pB0 + (size_t)(half) * 131072 + (size_t)(tile) * 64; \
    u16* _d = lB0 + ((tile) & 1) * 16384 + (half) * 8192; \
    gl_lds16(_s, _d); \
    gl_lds16(_s + 65536, _d + 4096); }

__global__ __launch_bounds__(512, 2)
void gemm8_mlp(const u16* __restrict__ A, const u16* __restrict__ Bc,
               u16* __restrict__ H)
{
    __shared__ __align__(16) u16 As[32768];   // 2 buf x 2 half x 128 x 64
    __shared__ __align__(16) u16 Bs[32768];

    const int tid = threadIdx.x, lane = tid & 63, wid = tid >> 6;
    const int wr = wid >> 2, wc = wid & 3;
    const int r15 = lane & 15, ks = lane >> 4;
    const int m0 = blockIdx.y * 256, n0 = blockIdx.x * 256;

    // per-lane swizzled frag offsets: slot = (kf*4+ks) ^ (row&7)
    const int axor0 = ((ks) ^ (r15 & 7)) * 8;
    const int axor1 = ((4 + ks) ^ (r15 & 7)) * 8;
    const u16* Ab0 = As + wr * 8192 + r15 * 64;
    const u16* Ab1 = As + 16384 + wr * 8192 + r15 * 64;
    const u16* Bb0 = Bs + (wc >> 1) * 8192 + (wc & 1) * 4096 + r15 * 64;
    const u16* Bb1 = Bs + 16384 + (wc >> 1) * 8192 + (wc & 1) * 4096 + r15 * 64;

    // staging: thread t covers chunk q=t (rows 0..63) and q=512+t (rows 64..127)
    const int r0 = tid >> 3, c0 = (tid & 7) ^ (r0 & 7);
    const u16* pA0 = A  + (size_t)(m0 + r0) * 1024 + c0 * 8;
    const u16* pB0 = Bc + (size_t)(n0 + r0) * 1024 + c0 * 8;
    u16* lA0 = As + tid * 8;
    u16* lB0 = Bs + tid * 8;

    f32x4 acc[8][4];
#pragma unroll
    for (int m = 0; m < 8; ++m)
#pragma unroll
        for (int n = 0; n < 4; ++n)
            acc[m][n] = (f32x4){0.f, 0.f, 0.f, 0.f};

    bf16x8 Aq[4][2], Bq[2][2][2];

    // ---- prologue: tile0 (all 4 halves) + tile1 (B0,B1); keep tile1's 2 in flight
    STAGE_A(0, 0); STAGE_A(0, 1);
    STAGE_B(0, 0); STAGE_B(0, 1);
    STAGE_B(1, 0); STAGE_B(1, 1);
    asm volatile("s_waitcnt vmcnt(4)" ::: "memory");
    __builtin_amdgcn_s_barrier();
    asm volatile("" ::: "memory");
    __builtin_amdgcn_sched_barrier(0);

    for (int i = 0; i < 8; ++i) {
        const int t1 = 2 * i + 1;
        const int t2 = 2 * i + 2;
        const int t3 = 2 * i + 3;
        const bool st = (i < 7);      // t2<16 and t3<16

        // ---- phase 1: quad(0,0) of tile 2i (buf0)
        LDA(0, 0); LDB(0, 0);
        STAGE_A(t1, 0);
        MIDBAR; MM(0, 0); PBAR;
        // ---- phase 2: quad(0,1)
        LDB(0, 1);
        STAGE_A(t1, 1);
        MIDBAR; MM(0, 1); PBAR;
        // ---- phase 3: quad(1,1)
        LDA(0, 1);
        if (st) STAGE_B(t2, 0);
        MIDBAR; MM(1, 1); PBAR;
        // ---- phase 4: quad(1,0); retire tile 2i+1 (needed p5-8)
        if (st) STAGE_B(t2, 1);
        MIDBAR; MM(1, 0);
        if (i == 7) { VMBARN(0); } else { VMBARN(4); }

        // ---- phase 5: quad(0,0) of tile 2i+1 (buf1)
        LDA(1, 0); LDB(1, 0);
        if (st) STAGE_A(t2, 0);
        MIDBAR; MM(0, 0); PBAR;
        // ---- phase 6: quad(0,1)
        LDB(1, 1);
        if (st) STAGE_A(t2, 1);
        MIDBAR; MM(0, 1); PBAR;
        // ---- phase 7: quad(1,1)
        LDA(1, 1);
        if (st) STAGE_B(t3, 0);
        MIDBAR; MM(1, 1); PBAR;
        // ---- phase 8: quad(1,0); retire tile 2i+2 (needed next p1-4)
        if (st) STAGE_B(t3, 1);
        MIDBAR; MM(1, 0);
        VMBARN(4);
    }

    // ---- epilogue: silu(up)*gate, register-local pairs (n=2p gate, 2p+1 up)
    const int orow0 = m0 + wr * 128;
    const int ocol0 = (n0 >> 1) + wc * 32;
#pragma unroll
    for (int m = 0; m < 8; ++m) {
#pragma unroll
        for (int p = 0; p < 2; ++p) {
#pragma unroll
            for (int r = 0; r < 4; ++r) {
                const int row = orow0 + m * 16 + ks * 4 + r;
                const int col = ocol0 + p * 16 + r15;
                const float g = acc[m][2 * p][r];
                const float u = acc[m][2 * p + 1][r];
                H[(size_t)row * 4096 + col] = f2b(u / (1.f + __expf(-u)) * g);
            }
        }
    }
}

// ---------------------------------------------------------------------------
// RMSNorm: fp32 in, fp32 weight, bf16 out. One block/token, 256 thr x 4 elems
// ---------------------------------------------------------------------------
__global__ __launch_bounds__(256)
void rmsnorm_k(const float* __restrict__ xin, const float* __restrict__ w,
               u16* __restrict__ o)
{
    const int t = blockIdx.x;
    const int tid = threadIdx.x;
    float4 xv = ((const float4*)xin)[(size_t)t * 256 + tid];
    float ss = xv.x * xv.x + xv.y * xv.y + xv.z * xv.z + xv.w * xv.w;
#pragma unroll
    for (int off = 32; off > 0; off >>= 1) ss += __shfl_down(ss, off);
    __shared__ float red[4];
    const int lane = tid & 63, wv_ = tid >> 6;
    if (lane == 0) red[wv_] = ss;
    __syncthreads();
    const float tot = red[0] + red[1] + red[2] + red[3];
    const float inv = rsqrtf(tot * (1.f / 1024.f) + 1e-5f);
    float4 ww = ((const float4*)w)[tid];
    ushort4 ov;
    ov.x = f2b(xv.x * inv * ww.x);
    ov.y = f2b(xv.y * inv * ww.y);
    ov.z = f2b(xv.z * inv * ww.z);
    ov.w = f2b(xv.w * inv * ww.w);
    ((ushort4*)o)[(size_t)t * 256 + tid] = ov;
}

// ---------------------------------------------------------------------------
// RoPE tables + apply. Q scaled by 0.125*log2(e) so attn can use exp2.
// ---------------------------------------------------------------------------
#define QSCALE 0.18033688011112042f   // (1/sqrt(64)) * log2(e)

__global__ void rope_tab(float* __restrict__ cs, float* __restrict__ sn)
{
    const int s = blockIdx.x;
    const int i = threadIdx.x;
    const double inv = exp(-((double)(2 * i) / 64.0) * log(10000.0));
    const double ang = (double)s * inv;
    cs[s * 32 + i] = (float)cos(ang);
    sn[s * 32 + i] = (float)sin(ang);
}

__global__ __launch_bounds__(256)
void rope_apply(u16* __restrict__ qkv, const float* __restrict__ cs,
                const float* __restrict__ sn)
{
    const int t = blockIdx.x;
    const int s = t & (SEQ - 1);
    u16* row = qkv + (size_t)t * 3072;
    __shared__ float c_s[32], s_s[32];
    if (threadIdx.x < 32) {
        c_s[threadIdx.x] = cs[s * 32 + threadIdx.x];
        s_s[threadIdx.x] = sn[s * 32 + threadIdx.x];
    }
    __syncthreads();
#pragma unroll
    for (int rr = 0; rr < 2; rr++) {
        const int item = rr * 256 + threadIdx.x;
        const int hh = item >> 5, i = item & 31;
        const int f = hh * 64 + 2 * i;
        const float c = c_s[i], sv = s_s[i];
        float xe = b2f(row[f]), xo = b2f(row[f + 1]);
        row[f]     = f2b((xe * c - xo * sv) * QSCALE);   // Q: fold scale+log2e
        row[f + 1] = f2b((xo * c + xe * sv) * QSCALE);
        xe = b2f(row[1024 + f]); xo = b2f(row[1024 + f + 1]);
        row[1024 + f]     = f2b(xe * c - xo * sv);       // K: unscaled
        row[1024 + f + 1] = f2b(xo * c + xe * sv);
    }
}

// ---------------------------------------------------------------------------
// V pre-transpose: vt[bh][d][s] from qkv v-columns. LDS-tiled, one-shot.
// ---------------------------------------------------------------------------
__global__ __launch_bounds__(256)
void vtrans(const u16* __restrict__ qkv, u16* __restrict__ vt)
{
    __shared__ u16 Ld[64 * 264];
    const int bh = blockIdx.x, st = blockIdx.y;
    const int b = bh >> 4, h = bh & 15;
    const int tid = threadIdx.x;
    const u16* src = qkv + ((size_t)(b * SEQ + st * 256 + tid)) * 3072 + 2048 + h * 64;
    uint4 v[8];
#pragma unroll
    for (int c = 0; c < 8; c++) v[c] = *(const uint4*)(src + c * 8);
#pragma unroll
    for (int c = 0; c < 8; c++) {
        const u16* pv = (const u16*)&v[c];
#pragma unroll
        for (int j = 0; j < 8; j++)
            Ld[(c * 8 + j) * 264 + tid] = pv[j];
    }
    __syncthreads();
    u16* dst = vt + (size_t)bh * (64 * SEQ) + st * 256;
#pragma unroll
    for (int cc = 0; cc < 8; cc++) {
        const int c = cc * 256 + tid;
        const int d = c >> 5, t8 = (c & 31) * 8;
        *(uint4*)(dst + (size_t)d * SEQ + t8) = *(const uint4*)(&Ld[d * 264 + t8]);
    }
}

// ---------------------------------------------------------------------------
// Flash attention (causal), static-max softmax: P = exp2(s) directly (Q
// pre-scaled by 0.125*log2e). l via ones-column MFMA. Block = 512 thr,
// 2 q-tiles of 128 rows (qy, 15-qy).
// R7: KVBLK=128 — halve the barrier count (17 iters/block vs 34). LDS:
// K [128][72], V^T [64][136], P [8][16][136] = 69 KB; grid gives 2
// blocks/CU anyway so the LDS growth is occupancy-free. QK^T swapped
// (mfma(K,Q) = S^T, lane holds 4 consecutive k), computed in two 64-wide
// halves to keep st[4] register footprint. Mask only on the diagonal tile.
// Staging stays R1-style (regular loads between barriers; compiler
// prefetches — gl_lds variant measured +21 µs in R4, setprio +5 µs in R5).
// ---------------------------------------------------------------------------
__global__ __launch_bounds__(512)
void attn(const u16* __restrict__ qkv, const u16* __restrict__ vt,
          u16* __restrict__ ao)
{
    __shared__ __align__(16) u16 Ks[128 * 72];       // 18 KB  [kv_s][d]
    __shared__ __align__(16) u16 Vt[64 * 136];       // 17 KB  [d][kv_s]
    __shared__ __align__(16) u16 Ps[8][16 * 136];    // 34 KB  per-wave [q][k]

    const int bh = blockIdx.x;
    const int qy = blockIdx.y;                 // 0..7
    const int b = bh >> 4, h = bh & 15;
    const int tid = threadIdx.x, lane = tid & 63, wid = tid >> 6;
    const int am = lane & 15, grp = lane >> 4;
    const size_t tok0 = (size_t)b * SEQ;
    const u16* qbase = qkv + tok0 * 3072 + h * 64;
    const u16* kbase = qbase + 1024;
    const u16* vtg = vt + (size_t)bh * (64 * SEQ);

    union { uint4 u; bf16x8 b; } onesu;
    onesu.u = (uint4){0x3f803f80u, 0x3f803f80u, 0x3f803f80u, 0x3f803f80u};
    const bf16x8 ones = onesu.b;

    const int srow = tid >> 3, sc8 = (tid & 7) * 8;  // staging: row, col-chunk

#pragma unroll
    for (int tile = 0; tile < 2; tile++) {
        const int yt = tile == 0 ? qy : 15 - qy;
        const int qrow0 = yt * 128 + wid * 16;

        bf16x8 qf[2];
        {
            const u16* qp = qbase + (size_t)(qrow0 + am) * 3072 + grp * 8;
            qf[0] = *(const bf16x8*)(qp);
            qf[1] = *(const bf16x8*)(qp + 32);
        }

        f32x4 O[4], Ol;
#pragma unroll
        for (int j = 0; j < 4; j++) O[j] = (f32x4){0.f, 0.f, 0.f, 0.f};
        Ol = (f32x4){0.f, 0.f, 0.f, 0.f};

        const int ktend = yt * 128;            // diagonal kv-tile start
        for (int kt = 0; kt <= ktend; kt += 128) {
            __syncthreads();
            // K rows [kt, kt+128): thread covers rows srow and srow+64
            *(uint4*)(&Ks[srow * 72 + sc8]) =
                *(const uint4*)(kbase + (size_t)(kt + srow) * 3072 + sc8);
            *(uint4*)(&Ks[(srow + 64) * 72 + sc8]) =
                *(const uint4*)(kbase + (size_t)(kt + srow + 64) * 3072 + sc8);
            // V^T d-row srow, s-cols [kt, kt+128): two 64-wide chunks
            *(uint4*)(&Vt[srow * 136 + sc8]) =
                *(const uint4*)(vtg + (size_t)srow * SEQ + kt + sc8);
            *(uint4*)(&Vt[srow * 136 + 64 + sc8]) =
                *(const uint4*)(vtg + (size_t)srow * SEQ + kt + 64 + sc8);
            __syncthreads();

            const bool diag = (kt == ktend);
            u16* pw = &Ps[wid][0];

            // ---- QK^T swapped, two 64-wide k-halves (keeps st[4])
#pragma unroll
            for (int kh = 0; kh < 2; kh++) {
                f32x4 st[4];
#pragma unroll
                for (int kk = 0; kk < 4; kk++) {
                    const u16* kb = &Ks[(kh * 64 + kk * 16 + am) * 72 + grp * 8];
                    bf16x8 k0 = *(const bf16x8*)(kb);
                    bf16x8 k1 = *(const bf16x8*)(kb + 32);
                    f32x4 s = (f32x4){0.f, 0.f, 0.f, 0.f};
                    s = __builtin_amdgcn_mfma_f32_16x16x32_bf16(k0, qf[0], s, 0, 0, 0);
                    s = __builtin_amdgcn_mfma_f32_16x16x32_bf16(k1, qf[1], s, 0, 0, 0);
                    st[kk] = s;
                }
                if (diag) {                    // causal mask (lane: k rows, q=am)
                    const int qg = qrow0 + am;
#pragma unroll
                    for (int kk = 0; kk < 4; kk++) {
                        const int kb2 = kt + kh * 64 + kk * 16 + grp * 4;
#pragma unroll
                        for (int r = 0; r < 4; r++) {
                            if (kb2 + r > qg) st[kk][r] = -1e30f;
                        }
                    }
                }
#pragma unroll
                for (int kk = 0; kk < 4; kk++)
#pragma unroll
                    for (int r = 0; r < 4; r++)
                        st[kk][r] = exp2f(st[kk][r]);

                // packed b64 P-writes: row q=am, cols k
#pragma unroll
                for (int kk = 0; kk < 4; kk++) {
                    ushort4 pk;
                    pk.x = f2b_trunc(st[kk][0]);
                    pk.y = f2b_trunc(st[kk][1]);
                    pk.z = f2b_trunc(st[kk][2]);
                    pk.w = f2b_trunc(st[kk][3]);
                    *(ushort4*)(&pw[am * 136 + kh * 64 + kk * 16 + grp * 4]) = pk;
                }
            }
            asm volatile("s_waitcnt lgkmcnt(0)" ::: "memory");

            // ---- PV + ones-column l accumulation over 4 k-slots of 32
#pragma unroll
            for (int hh = 0; hh < 4; hh++) {
                bf16x8 pf = *(const bf16x8*)(&pw[am * 136 + hh * 32 + grp * 8]);
                Ol = __builtin_amdgcn_mfma_f32_16x16x32_bf16(pf, ones, Ol, 0, 0, 0);
#pragma unroll
                for (int jt = 0; jt < 4; jt++) {
                    bf16x8 vf = *(const bf16x8*)(
                        &Vt[(jt * 16 + am) * 136 + hh * 32 + grp * 8]);
                    O[jt] = __builtin_amdgcn_mfma_f32_16x16x32_bf16(
                        pf, vf, O[jt], 0, 0, 0);
                }
            }
        }

        // ---- epilogue for this q-tile
        u16* aorow = ao + (tok0 + qrow0) * 1024 + h * 64;
#pragma unroll
        for (int r = 0; r < 4; r++) {
            const int q = grp * 4 + r;
            const float invl = 1.f / Ol[r];
#pragma unroll
            for (int jt = 0; jt < 4; jt++)
                aorow[(size_t)q * 1024 + jt * 16 + am] = f2b(O[jt][r] * invl);
        }
    }
}

// ---------------------------------------------------------------------------
extern "C" void kernel_launch(void* const* d_in, const int* in_sizes, int n_in,
                              void* d_out, int out_size, void* d_ws, size_t ws_size,
                              hipStream_t stream)
{
    (void)in_sizes; (void)n_in; (void)out_size; (void)ws_size;
    const float* x     = (const float*)d_in[0];
    const float* wq    = (const float*)d_in[1];
    const float* wk    = (const float*)d_in[2];
    const float* wv    = (const float*)d_in[3];
    const float* wo    = (const float*)d_in[4];
    const float* ln1   = (const float*)d_in[5];
    const float* ln2   = (const float*)d_in[6];
    const float* wup   = (const float*)d_in[7];
    const float* wgate = (const float*)d_in[8];
    const float* wdown = (const float*)d_in[9];
    float* out = (float*)d_out;
    char* ws = (char*)d_ws;
    const size_t MB = 1024 * 1024;

    u16*   xn   = (u16*)(ws);
    u16*   ao   = (u16*)(ws);
    u16*   qkv  = (u16*)(ws + 16 * MB);
    u16*   hbuf = (u16*)(ws + 16 * MB);
    u16*   vtb  = (u16*)(ws + 64 * MB);
    float* x1   = (float*)(ws + 80 * MB);
    u16*   bwq  = (u16*)(ws + 112 * MB);
    u16*   bwk  = (u16*)(ws + 114 * MB);
    u16*   bwv  = (u16*)(ws + 116 * MB);
    u16*   bwo  = (u16*)(ws + 118 * MB);
    u16*   bwmu = (u16*)(ws + 120 * MB);             // gate/up interleaved, 16MB
    u16*   bwdn = (u16*)(ws + 136 * MB);
    float* cst  = (float*)(ws + 144 * MB);
    float* snt  = (float*)(ws + 144 * MB + 262144);

    cvt_all<<<16384, 256, 0, stream>>>(wq, wk, wv, wo, wup, wgate, wdown,
                                       bwq, bwk, bwv, bwo, bwmu, bwdn);

    rope_tab<<<SEQ, 32, 0, stream>>>(cst, snt);
    rmsnorm_k<<<NTOK, 256, 0, stream>>>(x, ln1, xn);
    gemm_bt<0><<<dim3(24, 64), 256, 0, stream>>>(xn, bwq, qkv, nullptr, NTOK, 3072, 1024, 3072, 0);
    rope_apply<<<NTOK, 256, 0, stream>>>(qkv, cst, snt);
    vtrans<<<dim3(64, 8), 256, 0, stream>>>(qkv, vtb);
    attn<<<dim3(64, 8), 512, 0, stream>>>(qkv, vtb, ao);
    gemm_bt<1><<<dim3(8, 64), 256, 0, stream>>>(ao, bwo, x1, x, NTOK, 1024, 1024, 1024, 0);
    rmsnorm_k<<<NTOK, 256, 0, stream>>>(x1, ln2, xn);
    gemm8_mlp<<<dim3(32, 32), 512, 0, stream>>>(xn, bwmu, hbuf);
    gemm_bt<1><<<dim3(8, 64), 256, 0, stream>>>(hbuf, bwdn, out, x1, NTOK, 1024, 4096, 1024, 0);
}

// Round 8
// 545.146 us; speedup vs baseline: 1.0769x; 1.0354x over previous
//
#include <hip/hip_runtime.h>
#include <stdint.h>

#define SEQ   2048
#define NTOK  8192   // 4 * 2048

typedef unsigned short u16;
typedef __bf16 bf16x8 __attribute__((ext_vector_type(8)));
typedef float  f32x4  __attribute__((ext_vector_type(4)));
typedef float  f32x16 __attribute__((ext_vector_type(16)));

__device__ __forceinline__ float b2f(u16 b) {
    union { unsigned u; float f; } v; v.u = ((unsigned)b) << 16; return v.f;
}
__device__ __forceinline__ u16 f2b(float f) {
    union { float f; unsigned u; } v; v.f = f;
    unsigned r = (v.u + 0x7fffu + ((v.u >> 16) & 1u)) >> 16;
    return (u16)r;
}
__device__ __forceinline__ u16 f2b_trunc(float f) {   // cheap, P >= 0
    union { float f; unsigned u; } v; v.f = f;
    return (u16)(v.u >> 16);
}

__device__ __forceinline__ void gl_lds16(const void* g, void* l) {
    __builtin_amdgcn_global_load_lds(
        (const __attribute__((address_space(1))) void*)g,
        (__attribute__((address_space(3))) void*)l,
        16, 0, 0);
}

// ---------------------------------------------------------------------------
// fp32 -> bf16 conversion, all 7 weight matrices in ONE dispatch.
// gate/up are interleaved into ONE combined matrix dmu[8192][1024]:
//   rows [32q..32q+16) = gate rows [16q..16q+16)
//   rows [32q+16..32q+32) = up rows [16q..16q+16)
// so the 8-phase MLP GEMM can pair gate/up register-locally (16-col frags).
// ---------------------------------------------------------------------------
__global__ __launch_bounds__(256)
void cvt_all(const float* __restrict__ wq, const float* __restrict__ wk,
             const float* __restrict__ wv, const float* __restrict__ wo,
             const float* __restrict__ wup, const float* __restrict__ wgt,
             const float* __restrict__ wdn,
             u16* __restrict__ dq, u16* __restrict__ dk, u16* __restrict__ dv,
             u16* __restrict__ dw, u16* __restrict__ dmu, u16* __restrict__ dd)
{
    const int bid = blockIdx.x;
    const float* s; u16* d; int osrc, odst;
    if (bid < 4096) {
        const int which = bid >> 10;
        osrc = odst = (bid & 1023) * 256 + threadIdx.x;
        s = which == 0 ? wq : which == 1 ? wk : which == 2 ? wv : wo;
        d = which == 0 ? dq : which == 1 ? dk : which == 2 ? dv : dw;
    } else {
        const int which = (bid - 4096) >> 12;     // 0=up 1=gate 2=down
        const int o = ((bid - 4096) & 4095) * 256 + threadIdx.x;
        osrc = o;
        if (which == 2) { s = wdn; d = dd; odst = o; }
        else {
            s = which == 0 ? wup : wgt;
            d = dmu;
            const int row = o >> 8;               // 256 float4 per 1024-col row
            const int rowp = ((row >> 4) << 5) + (row & 15) + (which == 0 ? 16 : 0);
            odst = rowp * 256 + (o & 255);
        }
    }
    float4 v = ((const float4*)s)[osrc];
    ushort4 ov;
    ov.x = f2b(v.x); ov.y = f2b(v.y); ov.z = f2b(v.z); ov.w = f2b(v.w);
    ((ushort4*)d)[odst] = ov;
}

// ---------------------------------------------------------------------------
// GEMM: C[M][N] = A[M][K] * B[N][K]^T   (bf16 in, fp32 accum)
// 128x128 tile, BK=64, XOR-swizzled LDS, mfma 32x32x16.
// EPI 0: bf16 C[idx] = acc
// EPI 1: f32  C[idx] = acc + E_f32[idx]          (fused residual, fp32 out)
// ---------------------------------------------------------------------------
template<int EPI>
__global__ __launch_bounds__(256)
void gemm_bt(const u16* __restrict__ A, const u16* __restrict__ B,
             void* __restrict__ C, const void* __restrict__ E,
             int M, int N, int K, int ldc, int coff)
{
    __shared__ __align__(16) u16 As[128 * 64];
    __shared__ __align__(16) u16 Bs[128 * 64];

    const int tid  = threadIdx.x;
    const int lane = tid & 63;
    const int wid  = tid >> 6;
    const int m0 = blockIdx.y * 128;
    const int n0 = blockIdx.x * 128;
    const int wm = (wid >> 1) * 64;
    const int wn = (wid & 1) * 64;
    const int l31 = lane & 31, kg = lane >> 5;

    f32x16 acc[2][2];
#pragma unroll
    for (int i = 0; i < 2; i++)
#pragma unroll
        for (int j = 0; j < 2; j++)
#pragma unroll
            for (int r = 0; r < 16; r++) acc[i][j][r] = 0.f;

    const u16* Ag[4]; const u16* Bg[4]; u16* Al[4]; u16* Bl[4];
#pragma unroll
    for (int j = 0; j < 4; j++) {
        const int q = j * 256 + tid;
        const int r = q >> 3, s = q & 7, c = s ^ (r & 7);
        Ag[j] = A + (size_t)(m0 + r) * K + c * 8;
        Bg[j] = B + (size_t)(n0 + r) * K + c * 8;
        Al[j] = As + q * 8;
        Bl[j] = Bs + q * 8;
    }

    int arow[2], brow[2];
#pragma unroll
    for (int i = 0; i < 2; i++) { arow[i] = wm + i * 32 + l31; }
#pragma unroll
    for (int j = 0; j < 2; j++) { brow[j] = wn + j * 32 + l31; }

    for (int kt = 0; kt < K; kt += 64) {
        __syncthreads();
#pragma unroll
        for (int j = 0; j < 4; j++) {
            gl_lds16(Ag[j] + kt, Al[j]);
            gl_lds16(Bg[j] + kt, Bl[j]);
        }
        __syncthreads();

#pragma unroll
        for (int s = 0; s < 4; s++) {
            const int ch = s * 2 + kg;
            bf16x8 af[2], bf[2];
#pragma unroll
            for (int i = 0; i < 2; i++)
                af[i] = *(const bf16x8*)(
                    &As[arow[i] * 64 + ((ch ^ (arow[i] & 7)) * 8)]);
#pragma unroll
            for (int j = 0; j < 2; j++)
                bf[j] = *(const bf16x8*)(
                    &Bs[brow[j] * 64 + ((ch ^ (brow[j] & 7)) * 8)]);
#pragma unroll
            for (int i = 0; i < 2; i++)
#pragma unroll
                for (int j = 0; j < 2; j++)
                    acc[i][j] = __builtin_amdgcn_mfma_f32_32x32x16_bf16(
                        af[i], bf[j], acc[i][j], 0, 0, 0);
        }
    }

#pragma unroll
    for (int i = 0; i < 2; i++) {
#pragma unroll
        for (int r = 0; r < 16; r++) {
            const int row = m0 + wm + i * 32 + (r & 3) + 8 * (r >> 2) + 4 * kg;
#pragma unroll
            for (int j = 0; j < 2; j++) {
                const int col = n0 + wn + j * 32 + l31;
                const size_t idx = (size_t)row * ldc + coff + col;
                const float v = acc[i][j][r];
                if (EPI == 0) {
                    ((u16*)C)[idx] = f2b(v);
                } else {
                    ((float*)C)[idx] = v + ((const float*)E)[idx];
                }
            }
        }
    }
}

// ---------------------------------------------------------------------------
// Shared 8-phase scheduling macros (validated in gemm8_mlp, R0/R1 passes).
// ---------------------------------------------------------------------------
#define MIDBAR \
    __builtin_amdgcn_s_barrier(); \
    asm volatile("s_waitcnt lgkmcnt(0)" ::: "memory"); \
    __builtin_amdgcn_sched_barrier(0);

#define PBAR \
    __builtin_amdgcn_s_barrier(); \
    asm volatile("" ::: "memory"); \
    __builtin_amdgcn_sched_barrier(0);

#define VMBARN(n) \
    asm volatile("s_waitcnt vmcnt(" #n ")" ::: "memory"); \
    __builtin_amdgcn_s_barrier(); \
    asm volatile("" ::: "memory"); \
    __builtin_amdgcn_sched_barrier(0);

// ---------------------------------------------------------------------------
// 8-phase 256x256 MLP GEMM (gate+up combined, N=8192 interleaved), BK=64.
// R8: 4 m-tiles PER BLOCK (grid 32x8 = 256 blocks = exactly one residency
// wave at 1 block/CU; LDS 128 KB). Each block runs a seamless 64-K-tile
// pipeline — staging tile index T in [0,64): A row-block = T>>4, K-col =
// T&15; B restages per m-half (T&15 wraps). Register-only epilogue
// (silu(up)*gate store + acc re-zero) between barriers every 16 tiles.
// vmcnt invariants unchanged; true end (T>=64) drains with vmcnt(0).
// ---------------------------------------------------------------------------
#define LDA(bufi, mh) { \
    const u16* _ab = Ab##bufi + (mh) * 4096; \
    _Pragma("unroll") \
    for (int _m = 0; _m < 4; ++_m) { \
        Aq[_m][0] = *(const bf16x8*)(_ab + _m * 1024 + axor0); \
        Aq[_m][1] = *(const bf16x8*)(_ab + _m * 1024 + axor1); \
    } }

#define LDB(bufi, nh) { \
    const u16* _bb = Bb##bufi + (nh) * 2048; \
    _Pragma("unroll") \
    for (int _n = 0; _n < 2; ++_n) { \
        Bq[nh][_n][0] = *(const bf16x8*)(_bb + _n * 1024 + axor0); \
        Bq[nh][_n][1] = *(const bf16x8*)(_bb + _n * 1024 + axor1); \
    } }

#define MM(mh, nh) \
    __builtin_amdgcn_s_setprio(1); \
    { _Pragma("unroll") \
      for (int _m = 0; _m < 4; ++_m) { \
        _Pragma("unroll") \
        for (int _n = 0; _n < 2; ++_n) { \
            acc[(mh)*4+_m][(nh)*2+_n] = __builtin_amdgcn_mfma_f32_16x16x32_bf16( \
                Aq[_m][0], Bq[nh][_n][0], acc[(mh)*4+_m][(nh)*2+_n], 0, 0, 0); \
            acc[(mh)*4+_m][(nh)*2+_n] = __builtin_amdgcn_mfma_f32_16x16x32_bf16( \
                Aq[_m][1], Bq[nh][_n][1], acc[(mh)*4+_m][(nh)*2+_n], 0, 0, 0); \
        } } } \
    __builtin_amdgcn_s_setprio(0);

// T in [0,64): A source row-block = (T>>4)*256 rows, K-col = (T&15)*64.
#define STAGE_A(T, half) { \
    const u16* _s = pA0 + (size_t)((T) >> 4) * 262144 \
                        + (size_t)((T) & 15) * 64 + (size_t)(half) * 131072; \
    u16* _d = lA0 + ((T) & 1) * 16384 + (half) * 8192; \
    gl_lds16(_s, _d); \
    gl_lds16(_s + 65536, _d + 4096); }

#define STAGE_B(T, half) { \
    const u16* _s = pB0 + (size_t)((T) & 15) * 64 + (size_t)(half) * 131072; \
    u16* _d = lB0 + ((T) & 1) * 16384 + (half) * 8192; \
    gl_lds16(_s, _d); \
    gl_lds16(_s + 65536, _d + 4096); }

__global__ __launch_bounds__(512, 2)
void gemm8_mlp(const u16* __restrict__ A, const u16* __restrict__ Bc,
               u16* __restrict__ H)
{
    __shared__ __align__(16) u16 As[32768];   // 2 buf x 2 half x 128 x 64
    __shared__ __align__(16) u16 Bs[32768];

    const int tid = threadIdx.x, lane = tid & 63, wid = tid >> 6;
    const int wr = wid >> 2, wc = wid & 3;
    const int r15 = lane & 15, ks = lane >> 4;
    const int m0 = blockIdx.y * 1024, n0 = blockIdx.x * 256;

    // per-lane swizzled frag offsets: slot = (kf*4+ks) ^ (row&7)
    const int axor0 = ((ks) ^ (r15 & 7)) * 8;
    const int axor1 = ((4 + ks) ^ (r15 & 7)) * 8;
    const u16* Ab0 = As + wr * 8192 + r15 * 64;
    const u16* Ab1 = As + 16384 + wr * 8192 + r15 * 64;
    const u16* Bb0 = Bs + (wc >> 1) * 8192 + (wc & 1) * 4096 + r15 * 64;
    const u16* Bb1 = Bs + 16384 + (wc >> 1) * 8192 + (wc & 1) * 4096 + r15 * 64;

    // staging: thread t covers chunk q=t (rows 0..63) and q=512+t (rows 64..127)
    const int r0 = tid >> 3, c0 = (tid & 7) ^ (r0 & 7);
    const u16* pA0 = A  + (size_t)(m0 + r0) * 1024 + c0 * 8;
    const u16* pB0 = Bc + (size_t)(n0 + r0) * 1024 + c0 * 8;
    u16* lA0 = As + tid * 8;
    u16* lB0 = Bs + tid * 8;

    f32x4 acc[8][4];
#pragma unroll
    for (int m = 0; m < 8; ++m)
#pragma unroll
        for (int n = 0; n < 4; ++n)
            acc[m][n] = (f32x4){0.f, 0.f, 0.f, 0.f};

    bf16x8 Aq[4][2], Bq[2][2][2];

    // ---- prologue: tile0 (all 4 halves) + tile1 (B0,B1); keep tile1's 2 in flight
    STAGE_A(0, 0); STAGE_A(0, 1);
    STAGE_B(0, 0); STAGE_B(0, 1);
    STAGE_B(1, 0); STAGE_B(1, 1);
    asm volatile("s_waitcnt vmcnt(4)" ::: "memory");
    __builtin_amdgcn_s_barrier();
    asm volatile("" ::: "memory");
    __builtin_amdgcn_sched_barrier(0);

    for (int hm = 0; hm < 4; ++hm) {
        const int base = hm * 16;
        for (int i = 0; i < 8; ++i) {
            const int t1 = base + 2 * i + 1;
            const int t2 = base + 2 * i + 2;
            const int t3 = base + 2 * i + 3;
            const bool s2 = (t2 < 64);
            const bool s3 = (t3 < 64);

            // ---- phase 1: quad(0,0) of tile base+2i (buf0)
            LDA(0, 0); LDB(0, 0);
            STAGE_A(t1, 0);
            MIDBAR; MM(0, 0); PBAR;
            // ---- phase 2: quad(0,1)
            LDB(0, 1);
            STAGE_A(t1, 1);
            MIDBAR; MM(0, 1); PBAR;
            // ---- phase 3: quad(1,1)
            LDA(0, 1);
            if (s2) STAGE_B(t2, 0);
            MIDBAR; MM(1, 1); PBAR;
            // ---- phase 4: quad(1,0); retire tile t1 (needed p5-8)
            if (s2) STAGE_B(t2, 1);
            MIDBAR; MM(1, 0);
            if (s2) { VMBARN(4); } else { VMBARN(0); }

            // ---- phase 5: quad(0,0) of tile t1 (buf1)
            LDA(1, 0); LDB(1, 0);
            if (s2) STAGE_A(t2, 0);
            MIDBAR; MM(0, 0); PBAR;
            // ---- phase 6: quad(0,1)
            LDB(1, 1);
            if (s2) STAGE_A(t2, 1);
            MIDBAR; MM(0, 1); PBAR;
            // ---- phase 7: quad(1,1)
            LDA(1, 1);
            if (s3) STAGE_B(t3, 0);
            MIDBAR; MM(1, 1); PBAR;
            // ---- phase 8: quad(1,0); retire tile t2 (needed next p1-4)
            if (s3) STAGE_B(t3, 1);
            MIDBAR; MM(1, 0);
            VMBARN(4);
        }

        // ---- epilogue for m-half hm: silu(up)*gate, register-only; then
        //      re-zero acc. Runs between barriers; no LDS touched.
        const int orow0 = m0 + hm * 256 + wr * 128;
        const int ocol0 = (n0 >> 1) + wc * 32;
#pragma unroll
        for (int m = 0; m < 8; ++m) {
#pragma unroll
            for (int p = 0; p < 2; ++p) {
#pragma unroll
                for (int r = 0; r < 4; ++r) {
                    const int row = orow0 + m * 16 + ks * 4 + r;
                    const int col = ocol0 + p * 16 + r15;
                    const float g = acc[m][2 * p][r];
                    const float u = acc[m][2 * p + 1][r];
                    H[(size_t)row * 4096 + col] = f2b(u / (1.f + __expf(-u)) * g);
                }
            }
        }
#pragma unroll
        for (int m = 0; m < 8; ++m)
#pragma unroll
            for (int n = 0; n < 4; ++n)
                acc[m][n] = (f32x4){0.f, 0.f, 0.f, 0.f};
    }
}

// ---------------------------------------------------------------------------
// RMSNorm: fp32 in, fp32 weight, bf16 out. One block/token, 256 thr x 4 elems
// ---------------------------------------------------------------------------
__global__ __launch_bounds__(256)
void rmsnorm_k(const float* __restrict__ xin, const float* __restrict__ w,
               u16* __restrict__ o)
{
    const int t = blockIdx.x;
    const int tid = threadIdx.x;
    float4 xv = ((const float4*)xin)[(size_t)t * 256 + tid];
    float ss = xv.x * xv.x + xv.y * xv.y + xv.z * xv.z + xv.w * xv.w;
#pragma unroll
    for (int off = 32; off > 0; off >>= 1) ss += __shfl_down(ss, off);
    __shared__ float red[4];
    const int lane = tid & 63, wv_ = tid >> 6;
    if (lane == 0) red[wv_] = ss;
    __syncthreads();
    const float tot = red[0] + red[1] + red[2] + red[3];
    const float inv = rsqrtf(tot * (1.f / 1024.f) + 1e-5f);
    float4 ww = ((const float4*)w)[tid];
    ushort4 ov;
    ov.x = f2b(xv.x * inv * ww.x);
    ov.y = f2b(xv.y * inv * ww.y);
    ov.z = f2b(xv.z * inv * ww.z);
    ov.w = f2b(xv.w * inv * ww.w);
    ((ushort4*)o)[(size_t)t * 256 + tid] = ov;
}

// ---------------------------------------------------------------------------
// RoPE tables + apply. Q scaled by 0.125*log2(e) so attn can use exp2.
// ---------------------------------------------------------------------------
#define QSCALE 0.18033688011112042f   // (1/sqrt(64)) * log2(e)

__global__ void rope_tab(float* __restrict__ cs, float* __restrict__ sn)
{
    const int s = blockIdx.x;
    const int i = threadIdx.x;
    const double inv = exp(-((double)(2 * i) / 64.0) * log(10000.0));
    const double ang = (double)s * inv;
    cs[s * 32 + i] = (float)cos(ang);
    sn[s * 32 + i] = (float)sin(ang);
}

__global__ __launch_bounds__(256)
void rope_apply(u16* __restrict__ qkv, const float* __restrict__ cs,
                const float* __restrict__ sn)
{
    const int t = blockIdx.x;
    const int s = t & (SEQ - 1);
    u16* row = qkv + (size_t)t * 3072;
    __shared__ float c_s[32], s_s[32];
    if (threadIdx.x < 32) {
        c_s[threadIdx.x] = cs[s * 32 + threadIdx.x];
        s_s[threadIdx.x] = sn[s * 32 + threadIdx.x];
    }
    __syncthreads();
#pragma unroll
    for (int rr = 0; rr < 2; rr++) {
        const int item = rr * 256 + threadIdx.x;
        const int hh = item >> 5, i = item & 31;
        const int f = hh * 64 + 2 * i;
        const float c = c_s[i], sv = s_s[i];
        float xe = b2f(row[f]), xo = b2f(row[f + 1]);
        row[f]     = f2b((xe * c - xo * sv) * QSCALE);   // Q: fold scale+log2e
        row[f + 1] = f2b((xo * c + xe * sv) * QSCALE);
        xe = b2f(row[1024 + f]); xo = b2f(row[1024 + f + 1]);
        row[1024 + f]     = f2b(xe * c - xo * sv);       // K: unscaled
        row[1024 + f + 1] = f2b(xo * c + xe * sv);
    }
}

// ---------------------------------------------------------------------------
// V pre-transpose: vt[bh][d][s] from qkv v-columns. LDS-tiled, one-shot.
// ---------------------------------------------------------------------------
__global__ __launch_bounds__(256)
void vtrans(const u16* __restrict__ qkv, u16* __restrict__ vt)
{
    __shared__ u16 Ld[64 * 264];
    const int bh = blockIdx.x, st = blockIdx.y;
    const int b = bh >> 4, h = bh & 15;
    const int tid = threadIdx.x;
    const u16* src = qkv + ((size_t)(b * SEQ + st * 256 + tid)) * 3072 + 2048 + h * 64;
    uint4 v[8];
#pragma unroll
    for (int c = 0; c < 8; c++) v[c] = *(const uint4*)(src + c * 8);
#pragma unroll
    for (int c = 0; c < 8; c++) {
        const u16* pv = (const u16*)&v[c];
#pragma unroll
        for (int j = 0; j < 8; j++)
            Ld[(c * 8 + j) * 264 + tid] = pv[j];
    }
    __syncthreads();
    u16* dst = vt + (size_t)bh * (64 * SEQ) + st * 256;
#pragma unroll
    for (int cc = 0; cc < 8; cc++) {
        const int c = cc * 256 + tid;
        const int d = c >> 5, t8 = (c & 31) * 8;
        *(uint4*)(dst + (size_t)d * SEQ + t8) = *(const uint4*)(&Ld[d * 264 + t8]);
    }
}

// ---------------------------------------------------------------------------
// Flash attention (causal), static-max softmax: P = exp2(s) directly (Q
// pre-scaled by 0.125*log2e). l via ones-column MFMA. Block = 512 thr,
// 2 q-tiles of 128 rows (qy, 15-qy). KVBLK=128 (R7, best-known attn).
// QK^T swapped (mfma(K,Q) = S^T, lane holds 4 consecutive k), two 64-wide
// k-halves; packed b64 P-writes; mask only on the diagonal tile.
// ---------------------------------------------------------------------------
__global__ __launch_bounds__(512)
void attn(const u16* __restrict__ qkv, const u16* __restrict__ vt,
          u16* __restrict__ ao)
{
    __shared__ __align__(16) u16 Ks[128 * 72];       // 18 KB  [kv_s][d]
    __shared__ __align__(16) u16 Vt[64 * 136];       // 17 KB  [d][kv_s]
    __shared__ __align__(16) u16 Ps[8][16 * 136];    // 34 KB  per-wave [q][k]

    const int bh = blockIdx.x;
    const int qy = blockIdx.y;                 // 0..7
    const int b = bh >> 4, h = bh & 15;
    const int tid = threadIdx.x, lane = tid & 63, wid = tid >> 6;
    const int am = lane & 15, grp = lane >> 4;
    const size_t tok0 = (size_t)b * SEQ;
    const u16* qbase = qkv + tok0 * 3072 + h * 64;
    const u16* kbase = qbase + 1024;
    const u16* vtg = vt + (size_t)bh * (64 * SEQ);

    union { uint4 u; bf16x8 b; } onesu;
    onesu.u = (uint4){0x3f803f80u, 0x3f803f80u, 0x3f803f80u, 0x3f803f80u};
    const bf16x8 ones = onesu.b;

    const int srow = tid >> 3, sc8 = (tid & 7) * 8;  // staging: row, col-chunk

#pragma unroll
    for (int tile = 0; tile < 2; tile++) {
        const int yt = tile == 0 ? qy : 15 - qy;
        const int qrow0 = yt * 128 + wid * 16;

        bf16x8 qf[2];
        {
            const u16* qp = qbase + (size_t)(qrow0 + am) * 3072 + grp * 8;
            qf[0] = *(const bf16x8*)(qp);
            qf[1] = *(const bf16x8*)(qp + 32);
        }

        f32x4 O[4], Ol;
#pragma unroll
        for (int j = 0; j < 4; j++) O[j] = (f32x4){0.f, 0.f, 0.f, 0.f};
        Ol = (f32x4){0.f, 0.f, 0.f, 0.f};

        const int ktend = yt * 128;            // diagonal kv-tile start
        for (int kt = 0; kt <= ktend; kt += 128) {
            __syncthreads();
            // K rows [kt, kt+128): thread covers rows srow and srow+64
            *(uint4*)(&Ks[srow * 72 + sc8]) =
                *(const uint4*)(kbase + (size_t)(kt + srow) * 3072 + sc8);
            *(uint4*)(&Ks[(srow + 64) * 72 + sc8]) =
                *(const uint4*)(kbase + (size_t)(kt + srow + 64) * 3072 + sc8);
            // V^T d-row srow, s-cols [kt, kt+128): two 64-wide chunks
            *(uint4*)(&Vt[srow * 136 + sc8]) =
                *(const uint4*)(vtg + (size_t)srow * SEQ + kt + sc8);
            *(uint4*)(&Vt[srow * 136 + 64 + sc8]) =
                *(const uint4*)(vtg + (size_t)srow * SEQ + kt + 64 + sc8);
            __syncthreads();

            const bool diag = (kt == ktend);
            u16* pw = &Ps[wid][0];

            // ---- QK^T swapped, two 64-wide k-halves (keeps st[4])
#pragma unroll
            for (int kh = 0; kh < 2; kh++) {
                f32x4 st[4];
#pragma unroll
                for (int kk = 0; kk < 4; kk++) {
                    const u16* kb = &Ks[(kh * 64 + kk * 16 + am) * 72 + grp * 8];
                    bf16x8 k0 = *(const bf16x8*)(kb);
                    bf16x8 k1 = *(const bf16x8*)(kb + 32);
                    f32x4 s = (f32x4){0.f, 0.f, 0.f, 0.f};
                    s = __builtin_amdgcn_mfma_f32_16x16x32_bf16(k0, qf[0], s, 0, 0, 0);
                    s = __builtin_amdgcn_mfma_f32_16x16x32_bf16(k1, qf[1], s, 0, 0, 0);
                    st[kk] = s;
                }
                if (diag) {                    // causal mask (lane: k rows, q=am)
                    const int qg = qrow0 + am;
#pragma unroll
                    for (int kk = 0; kk < 4; kk++) {
                        const int kb2 = kt + kh * 64 + kk * 16 + grp * 4;
#pragma unroll
                        for (int r = 0; r < 4; r++) {
                            if (kb2 + r > qg) st[kk][r] = -1e30f;
                        }
                    }
                }
#pragma unroll
                for (int kk = 0; kk < 4; kk++)
#pragma unroll
                    for (int r = 0; r < 4; r++)
                        st[kk][r] = exp2f(st[kk][r]);

                // packed b64 P-writes: row q=am, cols k
#pragma unroll
                for (int kk = 0; kk < 4; kk++) {
                    ushort4 pk;
                    pk.x = f2b_trunc(st[kk][0]);
                    pk.y = f2b_trunc(st[kk][1]);
                    pk.z = f2b_trunc(st[kk][2]);
                    pk.w = f2b_trunc(st[kk][3]);
                    *(ushort4*)(&pw[am * 136 + kh * 64 + kk * 16 + grp * 4]) = pk;
                }
            }
            asm volatile("s_waitcnt lgkmcnt(0)" ::: "memory");

            // ---- PV + ones-column l accumulation over 4 k-slots of 32
#pragma unroll
            for (int hh = 0; hh < 4; hh++) {
                bf16x8 pf = *(const bf16x8*)(&pw[am * 136 + hh * 32 + grp * 8]);
                Ol = __builtin_amdgcn_mfma_f32_16x16x32_bf16(pf, ones, Ol, 0, 0, 0);
#pragma unroll
                for (int jt = 0; jt < 4; jt++) {
                    bf16x8 vf = *(const bf16x8*)(
                        &Vt[(jt * 16 + am) * 136 + hh * 32 + grp * 8]);
                    O[jt] = __builtin_amdgcn_mfma_f32_16x16x32_bf16(
                        pf, vf, O[jt], 0, 0, 0);
                }
            }
        }

        // ---- epilogue for this q-tile
        u16* aorow = ao + (tok0 + qrow0) * 1024 + h * 64;
#pragma unroll
        for (int r = 0; r < 4; r++) {
            const int q = grp * 4 + r;
            const float invl = 1.f / Ol[r];
#pragma unroll
            for (int jt = 0; jt < 4; jt++)
                aorow[(size_t)q * 1024 + jt * 16 + am] = f2b(O[jt][r] * invl);
        }
    }
}

// ---------------------------------------------------------------------------
extern "C" void kernel_launch(void* const* d_in, const int* in_sizes, int n_in,
                              void* d_out, int out_size, void* d_ws, size_t ws_size,
                              hipStream_t stream)
{
    (void)in_sizes; (void)n_in; (void)out_size; (void)ws_size;
    const float* x     = (const float*)d_in[0];
    const float* wq    = (const float*)d_in[1];
    const float* wk    = (const float*)d_in[2];
    const float* wv    = (const float*)d_in[3];
    const float* wo    = (const float*)d_in[4];
    const float* ln1   = (const float*)d_in[5];
    const float* ln2   = (const float*)d_in[6];
    const float* wup   = (const float*)d_in[7];
    const float* wgate = (const float*)d_in[8];
    const float* wdown = (const float*)d_in[9];
    float* out = (float*)d_out;
    char* ws = (char*)d_ws;
    const size_t MB = 1024 * 1024;

    u16*   xn   = (u16*)(ws);
    u16*   ao   = (u16*)(ws);
    u16*   qkv  = (u16*)(ws + 16 * MB);
    u16*   hbuf = (u16*)(ws + 16 * MB);
    u16*   vtb  = (u16*)(ws + 64 * MB);
    float* x1   = (float*)(ws + 80 * MB);
    u16*   bwq  = (u16*)(ws + 112 * MB);
    u16*   bwk  = (u16*)(ws + 114 * MB);
    u16*   bwv  = (u16*)(ws + 116 * MB);
    u16*   bwo  = (u16*)(ws + 118 * MB);
    u16*   bwmu = (u16*)(ws + 120 * MB);             // gate/up interleaved, 16MB
    u16*   bwdn = (u16*)(ws + 136 * MB);
    float* cst  = (float*)(ws + 144 * MB);
    float* snt  = (float*)(ws + 144 * MB + 262144);

    cvt_all<<<16384, 256, 0, stream>>>(wq, wk, wv, wo, wup, wgate, wdown,
                                       bwq, bwk, bwv, bwo, bwmu, bwdn);

    rope_tab<<<SEQ, 32, 0, stream>>>(cst, snt);
    rmsnorm_k<<<NTOK, 256, 0, stream>>>(x, ln1, xn);
    gemm_bt<0><<<dim3(24, 64), 256, 0, stream>>>(xn, bwq, qkv, nullptr, NTOK, 3072, 1024, 3072, 0);
    rope_apply<<<NTOK, 256, 0, stream>>>(qkv, cst, snt);
    vtrans<<<dim3(64, 8), 256, 0, stream>>>(qkv, vtb);
    attn<<<dim3(64, 8), 512, 0, stream>>>(qkv, vtb, ao);
    gemm_bt<1><<<dim3(8, 64), 256, 0, stream>>>(ao, bwo, x1, x, NTOK, 1024, 1024, 1024, 0);
    rmsnorm_k<<<NTOK, 256, 0, stream>>>(x1, ln2, xn);
    gemm8_mlp<<<dim3(32, 8), 512, 0, stream>>>(xn, bwmu, hbuf);
    gemm_bt<1><<<dim3(8, 64), 256, 0, stream>>>(hbuf, bwdn, out, x1, NTOK, 1024, 4096, 1024, 0);
}